// Round 1
// baseline (1269.847 us; speedup 1.0000x reference)
//
#include <hip/hip_runtime.h>

#define N_NODES 50000
#define N_EDGES 800000
#define SLOPE 0.15f

static __device__ __forceinline__ float leaky(float v) { return v > 0.f ? v : SLOPE * v; }

// ---------------- CSR build ----------------
__global__ void k_count(const int* __restrict__ dst, int* __restrict__ cnt) {
    int e = blockIdx.x * 256 + threadIdx.x;
    if (e < N_EDGES) atomicAdd(&cnt[dst[e]], 1);
}

// single-block exclusive scan over 50k counts; also emits cursor copy + 1/max(cnt,1)
__global__ void k_scan(const int* __restrict__ cnt, int* __restrict__ offs,
                       int* __restrict__ cursor, float* __restrict__ inv) {
    __shared__ int buf[1024];
    __shared__ int carry;
    const int n = N_NODES;
    int tid = threadIdx.x;
    if (tid == 0) carry = 0;
    __syncthreads();
    for (int base = 0; base < n; base += 1024) {
        int i = base + tid;
        int v = (i < n) ? cnt[i] : 0;
        buf[tid] = v;
        __syncthreads();
        for (int off = 1; off < 1024; off <<= 1) {
            int t = (tid >= off) ? buf[tid - off] : 0;
            __syncthreads();
            buf[tid] += t;
            __syncthreads();
        }
        int excl = buf[tid] - v;
        if (i < n) {
            int o = carry + excl;
            offs[i] = o;
            cursor[i] = o;
            inv[i] = 1.0f / (float)(v > 1 ? v : 1);
        }
        __syncthreads();
        if (tid == 0) carry += buf[1023];
        __syncthreads();
    }
    if (tid == 0) offs[n] = carry;
}

__global__ void k_fill(const int* __restrict__ src, const int* __restrict__ dst,
                       int* __restrict__ cursor, int* __restrict__ ssrc) {
    int e = blockIdx.x * 256 + threadIdx.x;
    if (e < N_EDGES) {
        int pos = atomicAdd(&cursor[dst[e]], 1);
        ssrc[pos] = src[e];
    }
}

// ---------------- mean aggregation: one wave per node, CPL cols per lane ----------------
template <int CPL>
__global__ __launch_bounds__(256) void k_agg(const float* __restrict__ tbl,
                                             const int* __restrict__ offs,
                                             const int* __restrict__ ssrc,
                                             const float* __restrict__ inv,
                                             float* __restrict__ out) {
    int wid = (blockIdx.x * 256 + threadIdx.x) >> 6;  // global wave id == node id
    if (wid >= N_NODES) return;                       // uniform per wave
    int lane = threadIdx.x & 63;
    const int D = CPL * 64;
    int beg = offs[wid], end = offs[wid + 1];
    float acc[CPL];
#pragma unroll
    for (int c = 0; c < CPL; ++c) acc[c] = 0.f;
    for (int e = beg; e < end; ++e) {
        const float* r = tbl + (size_t)ssrc[e] * D;
#pragma unroll
        for (int c = 0; c < CPL; ++c) acc[c] += r[lane + c * 64];
    }
    float w = inv[wid];
    float* o = out + (size_t)wid * D;
#pragma unroll
    for (int c = 0; c < CPL; ++c) o[lane + c * 64] = acc[c] * w;
}

// ---------------- fused fp32 GEMM: C = act(A1@B1 [+ A2@B2] [+ addend] [+ bias]) ----------
// 64x64 tile, BK=16, 256 threads, 4x4 micro-tile (contiguous), float4 LDS/global vectors.
// Requires: K % 16 == 0, N % 64 == 0. M guarded.
__global__ __launch_bounds__(256) void k_gemm(
    int M, int N,
    const float* __restrict__ A1, const float* __restrict__ B1, int K1,
    const float* __restrict__ A2, const float* __restrict__ B2, int K2,
    const float* __restrict__ addend, const float* __restrict__ bias,
    int act, float* __restrict__ C) {
    __shared__ float As[16][64];
    __shared__ float Bs[16][64];
    const int tid = threadIdx.x;
    const int tx4 = (tid & 15) * 4;   // col base of 4x4 micro-tile
    const int ty4 = (tid >> 4) * 4;   // row base of 4x4 micro-tile
    const int brow = blockIdx.y * 64;
    const int bcol = blockIdx.x * 64;

    const int lk  = tid & 15;         // A-load: k within tile
    const int lm4 = (tid >> 4) * 4;   // A-load: m base (4 rows)
    const int bk  = tid >> 4;         // B-load: k row
    const int bn4 = (tid & 15) * 4;   // B-load: n base (float4)

    float acc[4][4];
#pragma unroll
    for (int i = 0; i < 4; ++i)
#pragma unroll
        for (int j = 0; j < 4; ++j) acc[i][j] = 0.f;

#pragma unroll 1
    for (int phase = 0; phase < 2; ++phase) {
        const float* A = phase ? A2 : A1;
        const float* B = phase ? B2 : B1;
        const int K = phase ? K2 : K1;
        if (K == 0) continue;
        for (int k0 = 0; k0 < K; k0 += 16) {
            // stage A (4 coalesced scalar loads along k, rows lm4..lm4+3)
            float a0 = 0.f, a1 = 0.f, a2v = 0.f, a3 = 0.f;
            {
                int r0 = brow + lm4;
                const float* ap = A + (size_t)r0 * K + (k0 + lk);
                if (r0 + 0 < M) a0 = ap[0];
                if (r0 + 1 < M) a1 = ap[(size_t)K];
                if (r0 + 2 < M) a2v = ap[2 * (size_t)K];
                if (r0 + 3 < M) a3 = ap[3 * (size_t)K];
            }
            float4 bv = *(const float4*)(B + (size_t)(k0 + bk) * N + (bcol + bn4));
            __syncthreads();
            *(float4*)&As[lk][lm4] = make_float4(a0, a1, a2v, a3);
            *(float4*)&Bs[bk][bn4] = bv;
            __syncthreads();
#pragma unroll
            for (int kk = 0; kk < 16; ++kk) {
                float4 av = *(const float4*)&As[kk][ty4];
                float4 bw = *(const float4*)&Bs[kk][tx4];
                float aa[4] = {av.x, av.y, av.z, av.w};
                float bb[4] = {bw.x, bw.y, bw.z, bw.w};
#pragma unroll
                for (int i = 0; i < 4; ++i)
#pragma unroll
                    for (int j = 0; j < 4; ++j) acc[i][j] += aa[i] * bb[j];
            }
        }
    }

#pragma unroll
    for (int i = 0; i < 4; ++i) {
        int r = brow + ty4 + i;
        if (r >= M) continue;
        float v[4];
#pragma unroll
        for (int j = 0; j < 4; ++j) {
            v[j] = acc[i][j];
            if (bias) v[j] += bias[bcol + tx4 + j];
        }
        if (addend) {
            float4 ad = *(const float4*)(addend + (size_t)r * N + bcol + tx4);
            v[0] += ad.x; v[1] += ad.y; v[2] += ad.z; v[3] += ad.w;
        }
        if (act) {
#pragma unroll
            for (int j = 0; j < 4; ++j) v[j] = leaky(v[j]);
        }
        *(float4*)(C + (size_t)r * N + bcol + tx4) = make_float4(v[0], v[1], v[2], v[3]);
    }
}

// ---------------- fused head: [50k,64] -> pre_fc(32) -> leaky(fc1(32)) -> fc2(2) ----------
__global__ __launch_bounds__(256) void k_head(const float* __restrict__ h,
                                              const float* __restrict__ Wp, const float* __restrict__ bp,
                                              const float* __restrict__ Wf1, const float* __restrict__ bf1,
                                              const float* __restrict__ Wf2, const float* __restrict__ bf2,
                                              float* __restrict__ out) {
    __shared__ float sWp[64 * 32], sW1[32 * 32], sW2[32 * 2];
    __shared__ float sbp[32], sb1[32], sb2[2];
    int tid = threadIdx.x;
    for (int i = tid; i < 64 * 32; i += 256) sWp[i] = Wp[i];
    for (int i = tid; i < 32 * 32; i += 256) sW1[i] = Wf1[i];
    for (int i = tid; i < 64; i += 256) sW2[i] = Wf2[i];
    if (tid < 32) { sbp[tid] = bp[tid]; sb1[tid] = bf1[tid]; }
    if (tid < 2) sb2[tid] = bf2[tid];
    __syncthreads();
    int row = blockIdx.x * 256 + tid;
    if (row >= N_NODES) return;
    const float* hr = h + (size_t)row * 64;
    float xr[64];
#pragma unroll
    for (int i = 0; i < 64; ++i) xr[i] = hr[i];
    float h4[32];
    for (int o = 0; o < 32; ++o) {
        float s = sbp[o];
#pragma unroll
        for (int i = 0; i < 64; ++i) s += xr[i] * sWp[i * 32 + o];
        h4[o] = s;  // pre_fc: no activation
    }
    float h5[32];
    for (int o = 0; o < 32; ++o) {
        float s = sb1[o];
#pragma unroll
        for (int i = 0; i < 32; ++i) s += h4[i] * sW1[i * 32 + o];
        h5[o] = leaky(s);
    }
#pragma unroll
    for (int o = 0; o < 2; ++o) {
        float s = sb2[o];
#pragma unroll
        for (int i = 0; i < 32; ++i) s += h5[i] * sW2[i * 2 + o];
        out[(size_t)row * 2 + o] = s;
    }
}

// ---------------- launch ----------------
extern "C" void kernel_launch(void* const* d_in, const int* in_sizes, int n_in,
                              void* d_out, int out_size, void* d_ws, size_t ws_size,
                              hipStream_t stream) {
    const float* x   = (const float*)d_in[0];
    const int*   ei  = (const int*)d_in[1];
    // d_in[2..4] = edge_attr, We, be: dead code in the reference
    const float* W1l = (const float*)d_in[5];
    const float* b1  = (const float*)d_in[6];
    const float* W1r = (const float*)d_in[7];
    const float* W2l = (const float*)d_in[8];
    const float* b2  = (const float*)d_in[9];
    const float* W2r = (const float*)d_in[10];
    const float* W3l = (const float*)d_in[11];
    const float* b3  = (const float*)d_in[12];
    const float* W3r = (const float*)d_in[13];
    const float* Wp  = (const float*)d_in[14];
    const float* bp  = (const float*)d_in[15];
    const float* Wf1 = (const float*)d_in[16];
    const float* bf1 = (const float*)d_in[17];
    const float* Wf2 = (const float*)d_in[18];
    const float* bf2 = (const float*)d_in[19];
    float* out = (float*)d_out;
    (void)in_sizes; (void)n_in; (void)out_size; (void)ws_size;

    const int* src = ei;            // edge_index[0]
    const int* dst = ei + N_EDGES;  // edge_index[1]

    // bump allocator over d_ws (~235 MB total)
    char* base = (char*)d_ws;
    size_t off = 0;
    auto alloc = [&](size_t bytes) -> void* {
        void* r = base + off;
        off = (off + bytes + 255) & ~(size_t)255;
        return r;
    };
    int*   cnt    = (int*)alloc((size_t)N_NODES * 4);
    int*   offs   = (int*)alloc(((size_t)N_NODES + 1) * 4);
    int*   cursor = (int*)alloc((size_t)N_NODES * 4);
    float* inv    = (float*)alloc((size_t)N_NODES * 4);
    int*   ssrc   = (int*)alloc((size_t)N_EDGES * 4);
    float* aggX   = (float*)alloc((size_t)N_NODES * 128 * 4);  // also reused for z3|a3
    float* h1     = (float*)alloc((size_t)N_NODES * 512 * 4);  // also reused for h3
    float* z2     = (float*)alloc((size_t)N_NODES * 256 * 4);  // also reused for h2
    float* a2     = (float*)alloc((size_t)N_NODES * 256 * 4);
    float* z3 = aggX;
    float* a3 = aggX + (size_t)N_NODES * 64;
    float* h2 = z2;
    float* h3 = h1;

    // CSR build (d_ws is poisoned each call — rebuild every launch)
    hipMemsetAsync(cnt, 0, (size_t)N_NODES * 4, stream);
    k_count<<<(N_EDGES + 255) / 256, 256, 0, stream>>>(dst, cnt);
    k_scan<<<1, 1024, 0, stream>>>(cnt, offs, cursor, inv);
    k_fill<<<(N_EDGES + 255) / 256, 256, 0, stream>>>(src, dst, cursor, ssrc);

    const int aggGrid = (N_NODES + 3) / 4;      // 4 waves (nodes) per 256-thread block
    const int mT = (N_NODES + 63) / 64;

    // layer 1: agg x (dim 128), then h1 = leaky(aggX@W1l + x@W1r + b1)
    k_agg<2><<<aggGrid, 256, 0, stream>>>(x, offs, ssrc, inv, aggX);
    k_gemm<<<dim3(512 / 64, mT), 256, 0, stream>>>(N_NODES, 512,
        aggX, W1l, 128, x, W1r, 128, nullptr, b1, 1, h1);

    // layer 2: z2 = h1@W2l; a2 = S z2; h2 = leaky(h1@W2r + a2 + b2)
    k_gemm<<<dim3(256 / 64, mT), 256, 0, stream>>>(N_NODES, 256,
        h1, W2l, 512, nullptr, nullptr, 0, nullptr, nullptr, 0, z2);
    k_agg<4><<<aggGrid, 256, 0, stream>>>(z2, offs, ssrc, inv, a2);
    k_gemm<<<dim3(256 / 64, mT), 256, 0, stream>>>(N_NODES, 256,
        h1, W2r, 512, nullptr, nullptr, 0, a2, b2, 1, h2);

    // layer 3: z3 = h2@W3l; a3 = S z3; h3 = leaky(h2@W3r + a3 + b3)
    k_gemm<<<dim3(64 / 64, mT), 256, 0, stream>>>(N_NODES, 64,
        h2, W3l, 256, nullptr, nullptr, 0, nullptr, nullptr, 0, z3);
    k_agg<1><<<aggGrid, 256, 0, stream>>>(z3, offs, ssrc, inv, a3);
    k_gemm<<<dim3(1, mT), 256, 0, stream>>>(N_NODES, 64,
        h2, W3r, 256, nullptr, nullptr, 0, a3, b3, 1, h3);

    // head: pre_fc -> leaky(fc1) -> fc2
    k_head<<<(N_NODES + 255) / 256, 256, 0, stream>>>(h3, Wp, bp, Wf1, bf1, Wf2, bf2, out);
}

// Round 3
// 908.798 us; speedup vs baseline: 1.3973x; 1.3973x over previous
//
#include <hip/hip_runtime.h>

#define N_NODES 50000
#define N_EDGES 800000
#define SLOPE 0.15f

typedef unsigned short u16;
typedef __attribute__((ext_vector_type(8))) __bf16 bf16x8;
typedef __attribute__((ext_vector_type(4))) float f32x4;

static __device__ __forceinline__ float leaky(float v) { return v > 0.f ? v : SLOPE * v; }

// split fp32 into hi/lo bf16 pair: v ~= hi + lo, residual ~2^-17 relative
static __device__ __forceinline__ ushort2 split_bf(float v) {
    __bf16 h = (__bf16)v;
    float hf = (float)h;
    __bf16 l = (__bf16)(v - hf);
    ushort2 r;
    r.x = __builtin_bit_cast(unsigned short, h);
    r.y = __builtin_bit_cast(unsigned short, l);
    return r;
}

// ---------------- CSR build ----------------
__global__ void k_count(const int* __restrict__ dst, int* __restrict__ cnt) {
    int e = blockIdx.x * 256 + threadIdx.x;
    if (e < N_EDGES) atomicAdd(&cnt[dst[e]], 1);
}

__global__ void k_scan(const int* __restrict__ cnt, int* __restrict__ offs,
                       int* __restrict__ cursor, float* __restrict__ inv) {
    __shared__ int buf[1024];
    __shared__ int carry;
    const int n = N_NODES;
    int tid = threadIdx.x;
    if (tid == 0) carry = 0;
    __syncthreads();
    for (int base = 0; base < n; base += 1024) {
        int i = base + tid;
        int v = (i < n) ? cnt[i] : 0;
        buf[tid] = v;
        __syncthreads();
        for (int off = 1; off < 1024; off <<= 1) {
            int t = (tid >= off) ? buf[tid - off] : 0;
            __syncthreads();
            buf[tid] += t;
            __syncthreads();
        }
        int excl = buf[tid] - v;
        if (i < n) {
            int o = carry + excl;
            offs[i] = o;
            cursor[i] = o;
            inv[i] = 1.0f / (float)(v > 1 ? v : 1);
        }
        __syncthreads();
        if (tid == 0) carry += buf[1023];
        __syncthreads();
    }
    if (tid == 0) offs[n] = carry;
}

__global__ void k_fill(const int* __restrict__ src, const int* __restrict__ dst,
                       int* __restrict__ cursor, int* __restrict__ ssrc) {
    int e = blockIdx.x * 256 + threadIdx.x;
    if (e < N_EDGES) {
        int pos = atomicAdd(&cursor[dst[e]], 1);
        ssrc[pos] = src[e];
    }
}

// ---------------- mean aggregation ----------------
// one wave per node; G = 256/D edges processed per iteration (float4 per lane),
// cross-lane shfl_xor reduction at the end.
template <int D, bool SPLIT>
__global__ __launch_bounds__(256) void k_agg(const float* __restrict__ tbl,
                                             const int* __restrict__ offs,
                                             const int* __restrict__ ssrc,
                                             const float* __restrict__ inv,
                                             float* __restrict__ outf,
                                             u16* __restrict__ oh, u16* __restrict__ ol) {
    constexpr int G = 256 / D;    // edge groups per wave
    constexpr int LPG = 64 / G;   // lanes per group (= D/4)
    int wid = (blockIdx.x * 256 + threadIdx.x) >> 6;
    if (wid >= N_NODES) return;
    int lane = threadIdx.x & 63;
    int eg = lane / LPG;
    int cl = lane % LPG;
    int beg = offs[wid], end = offs[wid + 1];
    float a0 = 0.f, a1 = 0.f, a2 = 0.f, a3 = 0.f;
    for (int e = beg + eg; e < end; e += G) {
        const float4 v = *(const float4*)(tbl + (size_t)ssrc[e] * D + cl * 4);
        a0 += v.x; a1 += v.y; a2 += v.z; a3 += v.w;
    }
#pragma unroll
    for (int m = LPG; m < 64; m <<= 1) {
        a0 += __shfl_xor(a0, m, 64);
        a1 += __shfl_xor(a1, m, 64);
        a2 += __shfl_xor(a2, m, 64);
        a3 += __shfl_xor(a3, m, 64);
    }
    float wv = inv[wid];
    a0 *= wv; a1 *= wv; a2 *= wv; a3 *= wv;
    if (!SPLIT) {
        if (eg == 0) *(float4*)(outf + (size_t)wid * D + cl * 4) = make_float4(a0, a1, a2, a3);
    } else {
        // D=128 (G=2): lanes of group 0 write hi plane, group 1 writes lo plane
        ushort2 s0 = split_bf(a0), s1 = split_bf(a1), s2 = split_bf(a2), s3 = split_bf(a3);
        if (eg == 0) {
            *(ushort4*)(oh + (size_t)wid * D + cl * 4) = make_ushort4(s0.x, s1.x, s2.x, s3.x);
        } else if (eg == 1) {
            *(ushort4*)(ol + (size_t)wid * D + cl * 4) = make_ushort4(s0.y, s1.y, s2.y, s3.y);
        }
    }
}

// ---------------- operand prep ----------------
__global__ void k_xsplit(const float* __restrict__ in, u16* __restrict__ oh,
                         u16* __restrict__ ol, int n4) {
    int i = blockIdx.x * 256 + threadIdx.x;
    if (i >= n4) return;
    float4 v = ((const float4*)in)[i];
    ushort2 s0 = split_bf(v.x), s1 = split_bf(v.y), s2 = split_bf(v.z), s3 = split_bf(v.w);
    ((ushort4*)oh)[i] = make_ushort4(s0.x, s1.x, s2.x, s3.x);
    ((ushort4*)ol)[i] = make_ushort4(s0.y, s1.y, s2.y, s3.y);
}

// transpose + split all 6 weights in one dispatch (blockIdx.y selects weight)
__global__ void k_wsplit(const float* __restrict__ W0, const float* __restrict__ W1,
                         const float* __restrict__ W2, const float* __restrict__ W3,
                         const float* __restrict__ W4, const float* __restrict__ W5,
                         u16* o0h, u16* o0l, u16* o1h, u16* o1l, u16* o2h, u16* o2l,
                         u16* o3h, u16* o3l, u16* o4h, u16* o4l, u16* o5h, u16* o5l) {
    const float* W; u16 *oh, *ol; int K, N;
    switch (blockIdx.y) {
        case 0: W = W0; oh = o0h; ol = o0l; K = 128; N = 512; break;
        case 1: W = W1; oh = o1h; ol = o1l; K = 128; N = 512; break;
        case 2: W = W2; oh = o2h; ol = o2l; K = 512; N = 256; break;
        case 3: W = W3; oh = o3h; ol = o3l; K = 512; N = 256; break;
        case 4: W = W4; oh = o4h; ol = o4l; K = 256; N = 64; break;
        default: W = W5; oh = o5h; ol = o5l; K = 256; N = 64; break;
    }
    int i = blockIdx.x * 256 + threadIdx.x;
    if (i >= K * N) return;
    int k = i / N, n = i - k * N;
    ushort2 s = split_bf(W[i]);
    size_t o = (size_t)n * K + k;   // output is W^T [N][K]
    oh[o] = s.x;
    ol[o] = s.y;
}

// ---------------- split-bf16 MFMA GEMM ----------------
// C = act( A1@B1 [+ A2@B2] [+ addend] [+ bias] ), fp32-accurate via hi/lo split:
// A@B ~= Ah@Bh + Ah@Bl + Al@Bh  (3x mfma_f32_16x16x32_bf16, fp32 accum)
// Block: 256 thr (4 waves), tile 128x64; wave computes 32x64 (2x4 of 16x16 frags).
// B operands are pre-transposed [N][K]. K % 32 == 0, N % 64 == 0. M guarded.
#define LDA 40  // padded LDS row stride (ushorts) for a 32-wide k tile

__global__ __launch_bounds__(256) void k_gemm(
    int M, int N,
    const u16* __restrict__ A1h, const u16* __restrict__ A1l,
    const u16* __restrict__ B1h, const u16* __restrict__ B1l, int K1,
    const u16* __restrict__ A2h, const u16* __restrict__ A2l,
    const u16* __restrict__ B2h, const u16* __restrict__ B2l, int K2,
    const float* __restrict__ addend, const float* __restrict__ bias, int act,
    float* __restrict__ outf, u16* __restrict__ outh, u16* __restrict__ outl) {
    __shared__ u16 Ash[128 * LDA], Asl[128 * LDA], Bsh[64 * LDA], Bsl[64 * LDA];
    const int tid = threadIdx.x;
    const int lane = tid & 63;
    const int w = tid >> 6;
    const int fr = lane & 15;   // fragment row/col within 16x16
    const int q = lane >> 4;    // lane quad -> k chunk of 8
    const int brow = blockIdx.y * 128;
    const int bcol = blockIdx.x * 64;

    f32x4 acc[2][4] = {};

    for (int ph = 0; ph < 2; ++ph) {
        const u16* Ahp = ph ? A2h : A1h;
        const u16* Alp = ph ? A2l : A1l;
        const u16* Bhp = ph ? B2h : B1h;
        const u16* Blp = ph ? B2l : B1l;
        const int K = ph ? K2 : K1;
        if (K == 0) continue;
        for (int k0 = 0; k0 < K; k0 += 32) {
            __syncthreads();
            // stage A tile (128 rows x 32 k), hi+lo: 512 16B-chunks each, 2/thread
#pragma unroll
            for (int c0 = 0; c0 < 2; ++c0) {
                int c = tid + c0 * 256;
                int r = c >> 2, off = (c & 3) * 8;
                int gr = brow + r;
                uint4 vh = {0, 0, 0, 0}, vl = {0, 0, 0, 0};
                if (gr < M) {
                    size_t g = (size_t)gr * K + k0 + off;
                    vh = *(const uint4*)(Ahp + g);
                    vl = *(const uint4*)(Alp + g);
                }
                *(uint4*)&Ash[r * LDA + off] = vh;
                *(uint4*)&Asl[r * LDA + off] = vl;
            }
            // stage B tile (64 cols x 32 k from B^T), hi+lo: 256 chunks each, 1/thread
            {
                int r = tid >> 2, off = (tid & 3) * 8;
                size_t g = (size_t)(bcol + r) * K + k0 + off;
                *(uint4*)&Bsh[r * LDA + off] = *(const uint4*)(Bhp + g);
                *(uint4*)&Bsl[r * LDA + off] = *(const uint4*)(Blp + g);
            }
            __syncthreads();
            // fragments
            bf16x8 fah[2], fal[2], fbh[4], fbl[4];
#pragma unroll
            for (int rt = 0; rt < 2; ++rt) {
                int ad = (w * 32 + rt * 16 + fr) * LDA + q * 8;
                fah[rt] = __builtin_bit_cast(bf16x8, *(const uint4*)&Ash[ad]);
                fal[rt] = __builtin_bit_cast(bf16x8, *(const uint4*)&Asl[ad]);
            }
#pragma unroll
            for (int ct = 0; ct < 4; ++ct) {
                int ad = (ct * 16 + fr) * LDA + q * 8;
                fbh[ct] = __builtin_bit_cast(bf16x8, *(const uint4*)&Bsh[ad]);
                fbl[ct] = __builtin_bit_cast(bf16x8, *(const uint4*)&Bsl[ad]);
            }
#pragma unroll
            for (int rt = 0; rt < 2; ++rt)
#pragma unroll
                for (int ct = 0; ct < 4; ++ct) {
                    acc[rt][ct] = __builtin_amdgcn_mfma_f32_16x16x32_bf16(fah[rt], fbh[ct], acc[rt][ct], 0, 0, 0);
                    acc[rt][ct] = __builtin_amdgcn_mfma_f32_16x16x32_bf16(fah[rt], fbl[ct], acc[rt][ct], 0, 0, 0);
                    acc[rt][ct] = __builtin_amdgcn_mfma_f32_16x16x32_bf16(fal[rt], fbh[ct], acc[rt][ct], 0, 0, 0);
                }
        }
    }

    // epilogue: C/D layout col=lane&15, row=(lane>>4)*4+reg  [m89-verified]
#pragma unroll
    for (int rt = 0; rt < 2; ++rt) {
        int rowb = brow + w * 32 + rt * 16 + q * 4;
#pragma unroll
        for (int ct = 0; ct < 4; ++ct) {
            int col = bcol + ct * 16 + fr;
            float b = bias ? bias[col] : 0.f;
#pragma unroll
            for (int r = 0; r < 4; ++r) {
                int row = rowb + r;
                if (row >= M) continue;
                float v = acc[rt][ct][r] + b;
                if (addend) v += addend[(size_t)row * N + col];
                if (act) v = leaky(v);
                if (outf) outf[(size_t)row * N + col] = v;
                if (outh) {
                    ushort2 s = split_bf(v);
                    outh[(size_t)row * N + col] = s.x;
                    outl[(size_t)row * N + col] = s.y;
                }
            }
        }
    }
}

// ---------------- fused head ----------------
__global__ __launch_bounds__(256) void k_head(const float* __restrict__ h,
                                              const float* __restrict__ Wp, const float* __restrict__ bp,
                                              const float* __restrict__ Wf1, const float* __restrict__ bf1,
                                              const float* __restrict__ Wf2, const float* __restrict__ bf2,
                                              float* __restrict__ out) {
    __shared__ float sWp[64 * 32], sW1[32 * 32], sW2[32 * 2];
    __shared__ float sbp[32], sb1[32], sb2[2];
    int tid = threadIdx.x;
    for (int i = tid; i < 64 * 32; i += 256) sWp[i] = Wp[i];
    for (int i = tid; i < 32 * 32; i += 256) sW1[i] = Wf1[i];
    for (int i = tid; i < 64; i += 256) sW2[i] = Wf2[i];
    if (tid < 32) { sbp[tid] = bp[tid]; sb1[tid] = bf1[tid]; }
    if (tid < 2) sb2[tid] = bf2[tid];
    __syncthreads();
    int row = blockIdx.x * 256 + tid;
    if (row >= N_NODES) return;
    const float* hr = h + (size_t)row * 64;
    float xr[64];
#pragma unroll
    for (int i = 0; i < 64; ++i) xr[i] = hr[i];
    float h4[32];
    for (int o = 0; o < 32; ++o) {
        float s = sbp[o];
#pragma unroll
        for (int i = 0; i < 64; ++i) s += xr[i] * sWp[i * 32 + o];
        h4[o] = s;
    }
    float h5[32];
    for (int o = 0; o < 32; ++o) {
        float s = sb1[o];
#pragma unroll
        for (int i = 0; i < 32; ++i) s += h4[i] * sW1[i * 32 + o];
        h5[o] = leaky(s);
    }
#pragma unroll
    for (int o = 0; o < 2; ++o) {
        float s = sb2[o];
#pragma unroll
        for (int i = 0; i < 32; ++i) s += h5[i] * sW2[i * 2 + o];
        out[(size_t)row * 2 + o] = s;
    }
}

// ---------------- launch ----------------
extern "C" void kernel_launch(void* const* d_in, const int* in_sizes, int n_in,
                              void* d_out, int out_size, void* d_ws, size_t ws_size,
                              hipStream_t stream) {
    const float* x   = (const float*)d_in[0];
    const int*   ei  = (const int*)d_in[1];
    const float* W1l = (const float*)d_in[5];
    const float* b1  = (const float*)d_in[6];
    const float* W1r = (const float*)d_in[7];
    const float* W2l = (const float*)d_in[8];
    const float* b2  = (const float*)d_in[9];
    const float* W2r = (const float*)d_in[10];
    const float* W3l = (const float*)d_in[11];
    const float* b3  = (const float*)d_in[12];
    const float* W3r = (const float*)d_in[13];
    const float* Wp  = (const float*)d_in[14];
    const float* bp  = (const float*)d_in[15];
    const float* Wf1 = (const float*)d_in[16];
    const float* bf1 = (const float*)d_in[17];
    const float* Wf2 = (const float*)d_in[18];
    const float* bf2 = (const float*)d_in[19];
    float* out = (float*)d_out;
    (void)in_sizes; (void)n_in; (void)out_size; (void)ws_size;

    const int* src = ei;
    const int* dst = ei + N_EDGES;

    char* base = (char*)d_ws;
    size_t off = 0;
    auto alloc = [&](size_t bytes) -> void* {
        void* r = base + off;
        off = (off + bytes + 255) & ~(size_t)255;
        return r;
    };
    const size_t NN = N_NODES;
    int*   cnt    = (int*)alloc(NN * 4);
    int*   offs   = (int*)alloc((NN + 1) * 4);
    int*   cursor = (int*)alloc(NN * 4);
    float* inv    = (float*)alloc(NN * 4);
    int*   ssrc   = (int*)alloc((size_t)N_EDGES * 4);
    // split/transposed weights (~1.7 MB)
    u16* w1lh = (u16*)alloc(128 * 512 * 2); u16* w1ll = (u16*)alloc(128 * 512 * 2);
    u16* w1rh = (u16*)alloc(128 * 512 * 2); u16* w1rl = (u16*)alloc(128 * 512 * 2);
    u16* w2lh = (u16*)alloc(512 * 256 * 2); u16* w2ll = (u16*)alloc(512 * 256 * 2);
    u16* w2rh = (u16*)alloc(512 * 256 * 2); u16* w2rl = (u16*)alloc(512 * 256 * 2);
    u16* w3lh = (u16*)alloc(256 * 64 * 2);  u16* w3ll = (u16*)alloc(256 * 64 * 2);
    u16* w3rh = (u16*)alloc(256 * 64 * 2);  u16* w3rl = (u16*)alloc(256 * 64 * 2);

    // Live-range-aliased regions (total ~205 MB; round-0's 235 MB footprint passed)
    // Region A (51.2 MB): xh|xl|axh|axl  ->  z2 (fp32)  ->  h2h|h2l
    // Region B (102.4 MB): h1h|h1l
    // Region D (51.2 MB): a2 (fp32)  ->  z3f|a3f|h3f
    char* regA = (char*)alloc(NN * 256 * 4);
    char* regB = (char*)alloc(NN * 512 * 2 * 2);
    char* regD = (char*)alloc(NN * 256 * 4);

    u16* xh  = (u16*)regA;              // until L1 gemm
    u16* xl  = xh + NN * 128;
    u16* axh = xl + NN * 128;           // until L1 gemm
    u16* axl = axh + NN * 128;
    u16* h1h = (u16*)regB;              // until L2-right gemm done
    u16* h1l = h1h + NN * 512;
    float* z2 = (float*)regA;           // L2-left gemm -> agg2 (x/aggX dead)
    float* a2 = (float*)regD;           // agg2 -> L2-right gemm
    u16* h2h = (u16*)regA;              // L2-right gemm out (z2 dead) -> L3 gemms
    u16* h2l = h2h + NN * 256;
    float* z3f = (float*)regD;          // L3-left out (a2 dead)
    float* a3f = z3f + NN * 64;
    float* h3f = a3f + NN * 64;

    // CSR build (ws re-poisoned every call)
    hipMemsetAsync(cnt, 0, NN * 4, stream);
    k_count<<<(N_EDGES + 255) / 256, 256, 0, stream>>>(dst, cnt);
    k_scan<<<1, 1024, 0, stream>>>(cnt, offs, cursor, inv);
    k_fill<<<(N_EDGES + 255) / 256, 256, 0, stream>>>(src, dst, cursor, ssrc);

    // operand prep
    k_xsplit<<<(N_NODES * 128 / 4 + 255) / 256, 256, 0, stream>>>(x, xh, xl, N_NODES * 128 / 4);
    k_wsplit<<<dim3(512, 6), 256, 0, stream>>>(W1l, W1r, W2l, W2r, W3l, W3r,
        w1lh, w1ll, w1rh, w1rl, w2lh, w2ll, w2rh, w2rl, w3lh, w3ll, w3rh, w3rl);

    const int aggGrid = (N_NODES + 3) / 4;
    const int mT = (N_NODES + 127) / 128;

    // layer 1: aggX = S x (split out); h1 = leaky(aggX@W1l + x@W1r + b1) (split out)
    k_agg<128, true><<<aggGrid, 256, 0, stream>>>(x, offs, ssrc, inv, nullptr, axh, axl);
    k_gemm<<<dim3(8, mT), 256, 0, stream>>>(N_NODES, 512,
        axh, axl, w1lh, w1ll, 128, xh, xl, w1rh, w1rl, 128,
        nullptr, b1, 1, nullptr, h1h, h1l);

    // layer 2: z2 = h1@W2l (f32); a2 = S z2; h2 = leaky(h1@W2r + a2 + b2) (split out)
    k_gemm<<<dim3(4, mT), 256, 0, stream>>>(N_NODES, 256,
        h1h, h1l, w2lh, w2ll, 512, nullptr, nullptr, nullptr, nullptr, 0,
        nullptr, nullptr, 0, z2, nullptr, nullptr);
    k_agg<256, false><<<aggGrid, 256, 0, stream>>>(z2, offs, ssrc, inv, a2, nullptr, nullptr);
    k_gemm<<<dim3(4, mT), 256, 0, stream>>>(N_NODES, 256,
        h1h, h1l, w2rh, w2rl, 512, nullptr, nullptr, nullptr, nullptr, 0,
        a2, b2, 1, nullptr, h2h, h2l);

    // layer 3: z3 = h2@W3l (f32); a3 = S z3; h3 = leaky(h2@W3r + a3 + b3) (f32)
    k_gemm<<<dim3(1, mT), 256, 0, stream>>>(N_NODES, 64,
        h2h, h2l, w3lh, w3ll, 256, nullptr, nullptr, nullptr, nullptr, 0,
        nullptr, nullptr, 0, z3f, nullptr, nullptr);
    k_agg<64, false><<<aggGrid, 256, 0, stream>>>(z3f, offs, ssrc, inv, a3f, nullptr, nullptr);
    k_gemm<<<dim3(1, mT), 256, 0, stream>>>(N_NODES, 64,
        h2h, h2l, w3rh, w3rl, 256, nullptr, nullptr, nullptr, nullptr, 0,
        a3f, b3, 1, h3f, nullptr, nullptr);

    // head
    k_head<<<(N_NODES + 255) / 256, 256, 0, stream>>>(h3f, Wp, bp, Wf1, bf1, Wf2, bf2, out);
}

// Round 4
// 839.669 us; speedup vs baseline: 1.5123x; 1.0823x over previous
//
#include <hip/hip_runtime.h>

#define N_NODES 50000
#define N_EDGES 800000
#define SLOPE 0.15f

typedef unsigned short u16;
typedef __attribute__((ext_vector_type(8))) __bf16 bf16x8;
typedef __attribute__((ext_vector_type(4))) float f32x4;

static __device__ __forceinline__ float leaky(float v) { return v > 0.f ? v : SLOPE * v; }

// split fp32 into hi/lo bf16 pair: v ~= hi + lo, residual ~2^-17 relative
static __device__ __forceinline__ ushort2 split_bf(float v) {
    __bf16 h = (__bf16)v;
    float hf = (float)h;
    __bf16 l = (__bf16)(v - hf);
    ushort2 r;
    r.x = __builtin_bit_cast(unsigned short, h);
    r.y = __builtin_bit_cast(unsigned short, l);
    return r;
}

// async global->LDS 16B: HW writes lane's data to (wave-uniform lds base) + lane*16
static __device__ __forceinline__ void async_load16(const u16* g, u16* l) {
    __builtin_amdgcn_global_load_lds(
        (const __attribute__((address_space(1))) unsigned int*)g,
        (__attribute__((address_space(3))) unsigned int*)l, 16, 0, 0);
}

// ---------------- CSR build ----------------
__global__ void k_count(const int* __restrict__ dst, int* __restrict__ cnt) {
    int e = blockIdx.x * 256 + threadIdx.x;
    if (e < N_EDGES) atomicAdd(&cnt[dst[e]], 1);
}

__global__ void k_scan(const int* __restrict__ cnt, int* __restrict__ offs,
                       int* __restrict__ cursor, float* __restrict__ inv) {
    __shared__ int buf[1024];
    __shared__ int carry;
    const int n = N_NODES;
    int tid = threadIdx.x;
    if (tid == 0) carry = 0;
    __syncthreads();
    for (int base = 0; base < n; base += 1024) {
        int i = base + tid;
        int v = (i < n) ? cnt[i] : 0;
        buf[tid] = v;
        __syncthreads();
        for (int off = 1; off < 1024; off <<= 1) {
            int t = (tid >= off) ? buf[tid - off] : 0;
            __syncthreads();
            buf[tid] += t;
            __syncthreads();
        }
        int excl = buf[tid] - v;
        if (i < n) {
            int o = carry + excl;
            offs[i] = o;
            cursor[i] = o;
            inv[i] = 1.0f / (float)(v > 1 ? v : 1);
        }
        __syncthreads();
        if (tid == 0) carry += buf[1023];
        __syncthreads();
    }
    if (tid == 0) offs[n] = carry;
}

__global__ void k_fill(const int* __restrict__ src, const int* __restrict__ dst,
                       int* __restrict__ cursor, int* __restrict__ ssrc) {
    int e = blockIdx.x * 256 + threadIdx.x;
    if (e < N_EDGES) {
        int pos = atomicAdd(&cursor[dst[e]], 1);
        ssrc[pos] = src[e];
    }
}

// ---------------- mean aggregation ----------------
// one wave per node; G = 256/D edges processed per iteration (float4 per lane),
// unrolled x2 (independent accumulators) for memory-level parallelism.
template <int D, bool SPLIT>
__global__ __launch_bounds__(256) void k_agg(const float* __restrict__ tbl,
                                             const int* __restrict__ offs,
                                             const int* __restrict__ ssrc,
                                             const float* __restrict__ inv,
                                             float* __restrict__ outf,
                                             u16* __restrict__ oh, u16* __restrict__ ol) {
    constexpr int G = 256 / D;    // edge groups per wave
    constexpr int LPG = 64 / G;   // lanes per group (= D/4)
    int wid = (blockIdx.x * 256 + threadIdx.x) >> 6;
    if (wid >= N_NODES) return;
    int lane = threadIdx.x & 63;
    int eg = lane / LPG;
    int cl = lane % LPG;
    int beg = offs[wid], end = offs[wid + 1];
    float a0 = 0.f, a1 = 0.f, a2 = 0.f, a3 = 0.f;
    float b0 = 0.f, b1 = 0.f, b2 = 0.f, b3 = 0.f;
    int e = beg + eg;
    for (; e + G < end; e += 2 * G) {
        int s0 = ssrc[e], s1 = ssrc[e + G];
        const float4 v = *(const float4*)(tbl + (size_t)s0 * D + cl * 4);
        const float4 u = *(const float4*)(tbl + (size_t)s1 * D + cl * 4);
        a0 += v.x; a1 += v.y; a2 += v.z; a3 += v.w;
        b0 += u.x; b1 += u.y; b2 += u.z; b3 += u.w;
    }
    if (e < end) {
        const float4 v = *(const float4*)(tbl + (size_t)ssrc[e] * D + cl * 4);
        a0 += v.x; a1 += v.y; a2 += v.z; a3 += v.w;
    }
    a0 += b0; a1 += b1; a2 += b2; a3 += b3;
#pragma unroll
    for (int m = LPG; m < 64; m <<= 1) {
        a0 += __shfl_xor(a0, m, 64);
        a1 += __shfl_xor(a1, m, 64);
        a2 += __shfl_xor(a2, m, 64);
        a3 += __shfl_xor(a3, m, 64);
    }
    float wv = inv[wid];
    a0 *= wv; a1 *= wv; a2 *= wv; a3 *= wv;
    if (!SPLIT) {
        if (eg == 0) *(float4*)(outf + (size_t)wid * D + cl * 4) = make_float4(a0, a1, a2, a3);
    } else {
        ushort2 s0 = split_bf(a0), s1 = split_bf(a1), s2 = split_bf(a2), s3 = split_bf(a3);
        if (eg == 0) {
            *(ushort4*)(oh + (size_t)wid * D + cl * 4) = make_ushort4(s0.x, s1.x, s2.x, s3.x);
        } else if (eg == 1) {
            *(ushort4*)(ol + (size_t)wid * D + cl * 4) = make_ushort4(s0.y, s1.y, s2.y, s3.y);
        }
    }
}

// ---------------- operand prep ----------------
__global__ void k_xsplit(const float* __restrict__ in, u16* __restrict__ oh,
                         u16* __restrict__ ol, int n4) {
    int i = blockIdx.x * 256 + threadIdx.x;
    if (i >= n4) return;
    float4 v = ((const float4*)in)[i];
    ushort2 s0 = split_bf(v.x), s1 = split_bf(v.y), s2 = split_bf(v.z), s3 = split_bf(v.w);
    ((ushort4*)oh)[i] = make_ushort4(s0.x, s1.x, s2.x, s3.x);
    ((ushort4*)ol)[i] = make_ushort4(s0.y, s1.y, s2.y, s3.y);
}

// transpose + split all 6 weights in one dispatch (blockIdx.y selects weight)
__global__ void k_wsplit(const float* __restrict__ W0, const float* __restrict__ W1,
                         const float* __restrict__ W2, const float* __restrict__ W3,
                         const float* __restrict__ W4, const float* __restrict__ W5,
                         u16* o0h, u16* o0l, u16* o1h, u16* o1l, u16* o2h, u16* o2l,
                         u16* o3h, u16* o3l, u16* o4h, u16* o4l, u16* o5h, u16* o5l) {
    const float* W; u16 *oh, *ol; int K, N;
    switch (blockIdx.y) {
        case 0: W = W0; oh = o0h; ol = o0l; K = 128; N = 512; break;
        case 1: W = W1; oh = o1h; ol = o1l; K = 128; N = 512; break;
        case 2: W = W2; oh = o2h; ol = o2l; K = 512; N = 256; break;
        case 3: W = W3; oh = o3h; ol = o3l; K = 512; N = 256; break;
        case 4: W = W4; oh = o4h; ol = o4l; K = 256; N = 64; break;
        default: W = W5; oh = o5h; ol = o5l; K = 256; N = 64; break;
    }
    int i = blockIdx.x * 256 + threadIdx.x;
    if (i >= K * N) return;
    int k = i / N, n = i - k * N;
    ushort2 s = split_bf(W[i]);
    size_t o = (size_t)n * K + k;   // output is W^T [N][K]
    oh[o] = s.x;
    ol[o] = s.y;
}

// ---------------- split-bf16 MFMA GEMM, 128x128 tile, async staging ----------------
// C = act( A1@B1 [+ A2@B2] [+ addend] [+ bias] ); A@B ~= Ah@Bh + Ah@Bl + Al@Bh.
// 256 thr = 4 waves in 2x2; each wave 64x64 (4x4 16x16x32 frags).
// LDS: fragment-order row-major [128][32] per plane, staged via global_load_lds(16B).
// Requires K % 32 == 0, N % 128 == 0; M guarded via row clamp (garbage rows unwritten).
__global__ __launch_bounds__(256) void k_gemm128(
    int M, int N,
    const u16* __restrict__ A1h, const u16* __restrict__ A1l,
    const u16* __restrict__ B1h, const u16* __restrict__ B1l, int K1,
    const u16* __restrict__ A2h, const u16* __restrict__ A2l,
    const u16* __restrict__ B2h, const u16* __restrict__ B2l, int K2,
    const float* __restrict__ addend, const float* __restrict__ bias, int act,
    float* __restrict__ outf, u16* __restrict__ outh, u16* __restrict__ outl) {
    __shared__ u16 Ash[128 * 32], Asl[128 * 32], Bsh[128 * 32], Bsl[128 * 32];
    const int tid = threadIdx.x;
    const int lane = tid & 63;
    const int w = tid >> 6;
    const int wm = w & 1, wn = w >> 1;   // wave grid 2x2
    const int fr = lane & 15;
    const int q = lane >> 4;
    const int brow = blockIdx.y * 128;
    const int bcol = blockIdx.x * 128;

    f32x4 acc[4][4] = {};

    for (int ph = 0; ph < 2; ++ph) {
        const u16* Ahp = ph ? A2h : A1h;
        const u16* Alp = ph ? A2l : A1l;
        const u16* Bhp = ph ? B2h : B1h;
        const u16* Blp = ph ? B2l : B1l;
        const int K = ph ? K2 : K1;
        if (K == 0) continue;
        for (int k0 = 0; k0 < K; k0 += 32) {
            __syncthreads();  // prior reads done before overwrite
            // stage: per wave-iter, 64 lanes cover 64 consecutive 16B LDS chunks
#pragma unroll
            for (int i = 0; i < 2; ++i) {
                int c = (w * 2 + i) * 64 + lane;          // chunk 0..511
                int r = c >> 2, qq = c & 3;
                int ub = (w * 2 + i) * 512;               // lds ushort base (wave-uniform)
                int gr = brow + r; if (gr > M - 1) gr = M - 1;
                size_t ga = (size_t)gr * K + k0 + qq * 8;
                size_t gb = (size_t)(bcol + r) * K + k0 + qq * 8;
                async_load16(Ahp + ga, &Ash[ub]);
                async_load16(Alp + ga, &Asl[ub]);
                async_load16(Bhp + gb, &Bsh[ub]);
                async_load16(Blp + gb, &Bsl[ub]);
            }
            __syncthreads();  // vmcnt(0) drain + barrier
            bf16x8 fah[4], fal[4], fbh[4], fbl[4];
#pragma unroll
            for (int rt = 0; rt < 4; ++rt) {
                int ad = (wm * 64 + rt * 16 + fr) * 32 + q * 8;
                fah[rt] = __builtin_bit_cast(bf16x8, *(const uint4*)&Ash[ad]);
                fal[rt] = __builtin_bit_cast(bf16x8, *(const uint4*)&Asl[ad]);
            }
#pragma unroll
            for (int ct = 0; ct < 4; ++ct) {
                int ad = (wn * 64 + ct * 16 + fr) * 32 + q * 8;
                fbh[ct] = __builtin_bit_cast(bf16x8, *(const uint4*)&Bsh[ad]);
                fbl[ct] = __builtin_bit_cast(bf16x8, *(const uint4*)&Bsl[ad]);
            }
#pragma unroll
            for (int rt = 0; rt < 4; ++rt)
#pragma unroll
                for (int ct = 0; ct < 4; ++ct) {
                    acc[rt][ct] = __builtin_amdgcn_mfma_f32_16x16x32_bf16(fah[rt], fbh[ct], acc[rt][ct], 0, 0, 0);
                    acc[rt][ct] = __builtin_amdgcn_mfma_f32_16x16x32_bf16(fah[rt], fbl[ct], acc[rt][ct], 0, 0, 0);
                    acc[rt][ct] = __builtin_amdgcn_mfma_f32_16x16x32_bf16(fal[rt], fbh[ct], acc[rt][ct], 0, 0, 0);
                }
        }
    }

    // epilogue: frag C/D layout col=lane&15, row=q*4+reg  [m89]
#pragma unroll
    for (int rt = 0; rt < 4; ++rt) {
        int rowb = brow + wm * 64 + rt * 16 + q * 4;
#pragma unroll
        for (int ct = 0; ct < 4; ++ct) {
            int col = bcol + wn * 64 + ct * 16 + fr;
            float b = bias ? bias[col] : 0.f;
#pragma unroll
            for (int r = 0; r < 4; ++r) {
                int row = rowb + r;
                if (row >= M) continue;
                float v = acc[rt][ct][r] + b;
                if (addend) v += addend[(size_t)row * N + col];
                if (act) v = leaky(v);
                if (outf) outf[(size_t)row * N + col] = v;
                if (outh) {
                    ushort2 s = split_bf(v);
                    outh[(size_t)row * N + col] = s.x;
                    outl[(size_t)row * N + col] = s.y;
                }
            }
        }
    }
}

// ---------------- split-bf16 MFMA GEMM, 128x64 tile (for N=64 layer-3 gemms) ----------
#define LDA 40  // padded LDS row stride (ushorts)

__global__ __launch_bounds__(256) void k_gemm(
    int M, int N,
    const u16* __restrict__ A1h, const u16* __restrict__ A1l,
    const u16* __restrict__ B1h, const u16* __restrict__ B1l, int K1,
    const u16* __restrict__ A2h, const u16* __restrict__ A2l,
    const u16* __restrict__ B2h, const u16* __restrict__ B2l, int K2,
    const float* __restrict__ addend, const float* __restrict__ bias, int act,
    float* __restrict__ outf, u16* __restrict__ outh, u16* __restrict__ outl) {
    __shared__ u16 Ash[128 * LDA], Asl[128 * LDA], Bsh[64 * LDA], Bsl[64 * LDA];
    const int tid = threadIdx.x;
    const int lane = tid & 63;
    const int w = tid >> 6;
    const int fr = lane & 15;
    const int q = lane >> 4;
    const int brow = blockIdx.y * 128;
    const int bcol = blockIdx.x * 64;

    f32x4 acc[2][4] = {};

    for (int ph = 0; ph < 2; ++ph) {
        const u16* Ahp = ph ? A2h : A1h;
        const u16* Alp = ph ? A2l : A1l;
        const u16* Bhp = ph ? B2h : B1h;
        const u16* Blp = ph ? B2l : B1l;
        const int K = ph ? K2 : K1;
        if (K == 0) continue;
        for (int k0 = 0; k0 < K; k0 += 32) {
            __syncthreads();
#pragma unroll
            for (int c0 = 0; c0 < 2; ++c0) {
                int c = tid + c0 * 256;
                int r = c >> 2, off = (c & 3) * 8;
                int gr = brow + r;
                uint4 vh = {0, 0, 0, 0}, vl = {0, 0, 0, 0};
                if (gr < M) {
                    size_t g = (size_t)gr * K + k0 + off;
                    vh = *(const uint4*)(Ahp + g);
                    vl = *(const uint4*)(Alp + g);
                }
                *(uint4*)&Ash[r * LDA + off] = vh;
                *(uint4*)&Asl[r * LDA + off] = vl;
            }
            {
                int r = tid >> 2, off = (tid & 3) * 8;
                size_t g = (size_t)(bcol + r) * K + k0 + off;
                *(uint4*)&Bsh[r * LDA + off] = *(const uint4*)(Bhp + g);
                *(uint4*)&Bsl[r * LDA + off] = *(const uint4*)(Blp + g);
            }
            __syncthreads();
            bf16x8 fah[2], fal[2], fbh[4], fbl[4];
#pragma unroll
            for (int rt = 0; rt < 2; ++rt) {
                int ad = (w * 32 + rt * 16 + fr) * LDA + q * 8;
                fah[rt] = __builtin_bit_cast(bf16x8, *(const uint4*)&Ash[ad]);
                fal[rt] = __builtin_bit_cast(bf16x8, *(const uint4*)&Asl[ad]);
            }
#pragma unroll
            for (int ct = 0; ct < 4; ++ct) {
                int ad = (ct * 16 + fr) * LDA + q * 8;
                fbh[ct] = __builtin_bit_cast(bf16x8, *(const uint4*)&Bsh[ad]);
                fbl[ct] = __builtin_bit_cast(bf16x8, *(const uint4*)&Bsl[ad]);
            }
#pragma unroll
            for (int rt = 0; rt < 2; ++rt)
#pragma unroll
                for (int ct = 0; ct < 4; ++ct) {
                    acc[rt][ct] = __builtin_amdgcn_mfma_f32_16x16x32_bf16(fah[rt], fbh[ct], acc[rt][ct], 0, 0, 0);
                    acc[rt][ct] = __builtin_amdgcn_mfma_f32_16x16x32_bf16(fah[rt], fbl[ct], acc[rt][ct], 0, 0, 0);
                    acc[rt][ct] = __builtin_amdgcn_mfma_f32_16x16x32_bf16(fal[rt], fbh[ct], acc[rt][ct], 0, 0, 0);
                }
        }
    }

#pragma unroll
    for (int rt = 0; rt < 2; ++rt) {
        int rowb = brow + w * 32 + rt * 16 + q * 4;
#pragma unroll
        for (int ct = 0; ct < 4; ++ct) {
            int col = bcol + ct * 16 + fr;
            float b = bias ? bias[col] : 0.f;
#pragma unroll
            for (int r = 0; r < 4; ++r) {
                int row = rowb + r;
                if (row >= M) continue;
                float v = acc[rt][ct][r] + b;
                if (addend) v += addend[(size_t)row * N + col];
                if (act) v = leaky(v);
                if (outf) outf[(size_t)row * N + col] = v;
                if (outh) {
                    ushort2 s = split_bf(v);
                    outh[(size_t)row * N + col] = s.x;
                    outl[(size_t)row * N + col] = s.y;
                }
            }
        }
    }
}

// ---------------- fused head ----------------
__global__ __launch_bounds__(256) void k_head(const float* __restrict__ h,
                                              const float* __restrict__ Wp, const float* __restrict__ bp,
                                              const float* __restrict__ Wf1, const float* __restrict__ bf1,
                                              const float* __restrict__ Wf2, const float* __restrict__ bf2,
                                              float* __restrict__ out) {
    __shared__ float sWp[64 * 32], sW1[32 * 32], sW2[32 * 2];
    __shared__ float sbp[32], sb1[32], sb2[2];
    int tid = threadIdx.x;
    for (int i = tid; i < 64 * 32; i += 256) sWp[i] = Wp[i];
    for (int i = tid; i < 32 * 32; i += 256) sW1[i] = Wf1[i];
    for (int i = tid; i < 64; i += 256) sW2[i] = Wf2[i];
    if (tid < 32) { sbp[tid] = bp[tid]; sb1[tid] = bf1[tid]; }
    if (tid < 2) sb2[tid] = bf2[tid];
    __syncthreads();
    int row = blockIdx.x * 256 + tid;
    if (row >= N_NODES) return;
    const float* hr = h + (size_t)row * 64;
    float xr[64];
#pragma unroll
    for (int i = 0; i < 64; ++i) xr[i] = hr[i];
    float h4[32];
    for (int o = 0; o < 32; ++o) {
        float s = sbp[o];
#pragma unroll
        for (int i = 0; i < 64; ++i) s += xr[i] * sWp[i * 32 + o];
        h4[o] = s;
    }
    float h5[32];
    for (int o = 0; o < 32; ++o) {
        float s = sb1[o];
#pragma unroll
        for (int i = 0; i < 32; ++i) s += h4[i] * sW1[i * 32 + o];
        h5[o] = leaky(s);
    }
#pragma unroll
    for (int o = 0; o < 2; ++o) {
        float s = sb2[o];
#pragma unroll
        for (int i = 0; i < 32; ++i) s += h5[i] * sW2[i * 2 + o];
        out[(size_t)row * 2 + o] = s;
    }
}

// ---------------- launch ----------------
extern "C" void kernel_launch(void* const* d_in, const int* in_sizes, int n_in,
                              void* d_out, int out_size, void* d_ws, size_t ws_size,
                              hipStream_t stream) {
    const float* x   = (const float*)d_in[0];
    const int*   ei  = (const int*)d_in[1];
    const float* W1l = (const float*)d_in[5];
    const float* b1  = (const float*)d_in[6];
    const float* W1r = (const float*)d_in[7];
    const float* W2l = (const float*)d_in[8];
    const float* b2  = (const float*)d_in[9];
    const float* W2r = (const float*)d_in[10];
    const float* W3l = (const float*)d_in[11];
    const float* b3  = (const float*)d_in[12];
    const float* W3r = (const float*)d_in[13];
    const float* Wp  = (const float*)d_in[14];
    const float* bp  = (const float*)d_in[15];
    const float* Wf1 = (const float*)d_in[16];
    const float* bf1 = (const float*)d_in[17];
    const float* Wf2 = (const float*)d_in[18];
    const float* bf2 = (const float*)d_in[19];
    float* out = (float*)d_out;
    (void)in_sizes; (void)n_in; (void)out_size; (void)ws_size;

    const int* src = ei;
    const int* dst = ei + N_EDGES;

    char* base = (char*)d_ws;
    size_t off = 0;
    auto alloc = [&](size_t bytes) -> void* {
        void* r = base + off;
        off = (off + bytes + 255) & ~(size_t)255;
        return r;
    };
    const size_t NN = N_NODES;
    int*   cnt    = (int*)alloc(NN * 4);
    int*   offs   = (int*)alloc((NN + 1) * 4);
    int*   cursor = (int*)alloc(NN * 4);
    float* inv    = (float*)alloc(NN * 4);
    int*   ssrc   = (int*)alloc((size_t)N_EDGES * 4);
    u16* w1lh = (u16*)alloc(128 * 512 * 2); u16* w1ll = (u16*)alloc(128 * 512 * 2);
    u16* w1rh = (u16*)alloc(128 * 512 * 2); u16* w1rl = (u16*)alloc(128 * 512 * 2);
    u16* w2lh = (u16*)alloc(512 * 256 * 2); u16* w2ll = (u16*)alloc(512 * 256 * 2);
    u16* w2rh = (u16*)alloc(512 * 256 * 2); u16* w2rl = (u16*)alloc(512 * 256 * 2);
    u16* w3lh = (u16*)alloc(256 * 64 * 2);  u16* w3ll = (u16*)alloc(256 * 64 * 2);
    u16* w3rh = (u16*)alloc(256 * 64 * 2);  u16* w3rl = (u16*)alloc(256 * 64 * 2);

    // Live-range-aliased regions (total ~205 MB)
    char* regA = (char*)alloc(NN * 256 * 4);
    char* regB = (char*)alloc(NN * 512 * 2 * 2);
    char* regD = (char*)alloc(NN * 256 * 4);

    u16* xh  = (u16*)regA;
    u16* xl  = xh + NN * 128;
    u16* axh = xl + NN * 128;
    u16* axl = axh + NN * 128;
    u16* h1h = (u16*)regB;
    u16* h1l = h1h + NN * 512;
    float* z2 = (float*)regA;
    float* a2 = (float*)regD;
    u16* h2h = (u16*)regA;
    u16* h2l = h2h + NN * 256;
    float* z3f = (float*)regD;
    float* a3f = z3f + NN * 64;
    float* h3f = a3f + NN * 64;

    hipMemsetAsync(cnt, 0, NN * 4, stream);
    k_count<<<(N_EDGES + 255) / 256, 256, 0, stream>>>(dst, cnt);
    k_scan<<<1, 1024, 0, stream>>>(cnt, offs, cursor, inv);
    k_fill<<<(N_EDGES + 255) / 256, 256, 0, stream>>>(src, dst, cursor, ssrc);

    k_xsplit<<<(N_NODES * 128 / 4 + 255) / 256, 256, 0, stream>>>(x, xh, xl, N_NODES * 128 / 4);
    k_wsplit<<<dim3(512, 6), 256, 0, stream>>>(W1l, W1r, W2l, W2r, W3l, W3r,
        w1lh, w1ll, w1rh, w1rl, w2lh, w2ll, w2rh, w2rl, w3lh, w3ll, w3rh, w3rl);

    const int aggGrid = (N_NODES + 3) / 4;
    const int mT = (N_NODES + 127) / 128;

    // layer 1
    k_agg<128, true><<<aggGrid, 256, 0, stream>>>(x, offs, ssrc, inv, nullptr, axh, axl);
    k_gemm128<<<dim3(4, mT), 256, 0, stream>>>(N_NODES, 512,
        axh, axl, w1lh, w1ll, 128, xh, xl, w1rh, w1rl, 128,
        nullptr, b1, 1, nullptr, h1h, h1l);

    // layer 2
    k_gemm128<<<dim3(2, mT), 256, 0, stream>>>(N_NODES, 256,
        h1h, h1l, w2lh, w2ll, 512, nullptr, nullptr, nullptr, nullptr, 0,
        nullptr, nullptr, 0, z2, nullptr, nullptr);
    k_agg<256, false><<<aggGrid, 256, 0, stream>>>(z2, offs, ssrc, inv, a2, nullptr, nullptr);
    k_gemm128<<<dim3(2, mT), 256, 0, stream>>>(N_NODES, 256,
        h1h, h1l, w2rh, w2rl, 512, nullptr, nullptr, nullptr, nullptr, 0,
        a2, b2, 1, nullptr, h2h, h2l);

    // layer 3 (N=64: 128x64-tile kernel)
    k_gemm<<<dim3(1, mT), 256, 0, stream>>>(N_NODES, 64,
        h2h, h2l, w3lh, w3ll, 256, nullptr, nullptr, nullptr, nullptr, 0,
        nullptr, nullptr, 0, z3f, nullptr, nullptr);
    k_agg<64, false><<<aggGrid, 256, 0, stream>>>(z3f, offs, ssrc, inv, a3f, nullptr, nullptr);
    k_gemm<<<dim3(1, mT), 256, 0, stream>>>(N_NODES, 64,
        h2h, h2l, w3rh, w3rl, 256, nullptr, nullptr, nullptr, nullptr, 0,
        a3f, b3, 1, h3f, nullptr, nullptr);

    // head
    k_head<<<(N_NODES + 255) / 256, 256, 0, stream>>>(h3f, Wp, bp, Wf1, bf1, Wf2, bf2, out);
}

// Round 5
// 805.110 us; speedup vs baseline: 1.5772x; 1.0429x over previous
//
#include <hip/hip_runtime.h>

#define N_NODES 50000
#define N_EDGES 800000
#define SLOPE 0.15f

typedef unsigned short u16;
typedef __attribute__((ext_vector_type(8))) __bf16 bf16x8;
typedef __attribute__((ext_vector_type(4))) float f32x4;

static __device__ __forceinline__ float leaky(float v) { return v > 0.f ? v : SLOPE * v; }

// split fp32 into hi/lo bf16 pair: v ~= hi + lo, residual ~2^-17 relative
static __device__ __forceinline__ ushort2 split_bf(float v) {
    __bf16 h = (__bf16)v;
    float hf = (float)h;
    __bf16 l = (__bf16)(v - hf);
    ushort2 r;
    r.x = __builtin_bit_cast(unsigned short, h);
    r.y = __builtin_bit_cast(unsigned short, l);
    return r;
}

// async global->LDS 16B: HW writes lane's data to (wave-uniform lds base) + lane*16
static __device__ __forceinline__ void async_load16(const u16* g, u16* l) {
    __builtin_amdgcn_global_load_lds(
        (const __attribute__((address_space(1))) unsigned int*)g,
        (__attribute__((address_space(3))) unsigned int*)l, 16, 0, 0);
}

// ---------------- CSR build ----------------
__global__ void k_count(const int* __restrict__ dst, int* __restrict__ cnt) {
    int e = blockIdx.x * 256 + threadIdx.x;
    if (e < N_EDGES) atomicAdd(&cnt[dst[e]], 1);
}

__global__ void k_scan(const int* __restrict__ cnt, int* __restrict__ offs,
                       int* __restrict__ cursor, float* __restrict__ inv) {
    __shared__ int buf[1024];
    __shared__ int carry;
    const int n = N_NODES;
    int tid = threadIdx.x;
    if (tid == 0) carry = 0;
    __syncthreads();
    for (int base = 0; base < n; base += 1024) {
        int i = base + tid;
        int v = (i < n) ? cnt[i] : 0;
        buf[tid] = v;
        __syncthreads();
        for (int off = 1; off < 1024; off <<= 1) {
            int t = (tid >= off) ? buf[tid - off] : 0;
            __syncthreads();
            buf[tid] += t;
            __syncthreads();
        }
        int excl = buf[tid] - v;
        if (i < n) {
            int o = carry + excl;
            offs[i] = o;
            cursor[i] = o;
            inv[i] = 1.0f / (float)(v > 1 ? v : 1);
        }
        __syncthreads();
        if (tid == 0) carry += buf[1023];
        __syncthreads();
    }
    if (tid == 0) offs[n] = carry;
}

__global__ void k_fill(const int* __restrict__ src, const int* __restrict__ dst,
                       int* __restrict__ cursor, int* __restrict__ ssrc) {
    int e = blockIdx.x * 256 + threadIdx.x;
    if (e < N_EDGES) {
        int pos = atomicAdd(&cursor[dst[e]], 1);
        ssrc[pos] = src[e];
    }
}

// ---------------- mean aggregation ----------------
// one wave per node; G = 256/D edges per iteration group (float4 per lane),
// unrolled x4 (independent accumulators) for memory-level parallelism.
template <int D, bool SPLIT>
__global__ __launch_bounds__(256) void k_agg(const float* __restrict__ tbl,
                                             const int* __restrict__ offs,
                                             const int* __restrict__ ssrc,
                                             const float* __restrict__ inv,
                                             float* __restrict__ outf,
                                             u16* __restrict__ oh, u16* __restrict__ ol) {
    constexpr int G = 256 / D;    // edge groups per wave
    constexpr int LPG = 64 / G;   // lanes per group (= D/4)
    int wid = (blockIdx.x * 256 + threadIdx.x) >> 6;
    if (wid >= N_NODES) return;
    int lane = threadIdx.x & 63;
    int eg = lane / LPG;
    int cl = lane % LPG;
    int beg = offs[wid], end = offs[wid + 1];
    float x0 = 0.f, x1 = 0.f, x2 = 0.f, x3 = 0.f;
    float y0 = 0.f, y1 = 0.f, y2 = 0.f, y3 = 0.f;
    float z0 = 0.f, z1 = 0.f, z2 = 0.f, z3 = 0.f;
    float w0 = 0.f, w1 = 0.f, w2 = 0.f, w3 = 0.f;
    int e = beg + eg;
    for (; e + 3 * G < end; e += 4 * G) {
        int i0 = ssrc[e], i1 = ssrc[e + G], i2 = ssrc[e + 2 * G], i3 = ssrc[e + 3 * G];
        float4 v0 = *(const float4*)(tbl + (size_t)i0 * D + cl * 4);
        float4 v1 = *(const float4*)(tbl + (size_t)i1 * D + cl * 4);
        float4 v2 = *(const float4*)(tbl + (size_t)i2 * D + cl * 4);
        float4 v3 = *(const float4*)(tbl + (size_t)i3 * D + cl * 4);
        x0 += v0.x; x1 += v0.y; x2 += v0.z; x3 += v0.w;
        y0 += v1.x; y1 += v1.y; y2 += v1.z; y3 += v1.w;
        z0 += v2.x; z1 += v2.y; z2 += v2.z; z3 += v2.w;
        w0 += v3.x; w1 += v3.y; w2 += v3.z; w3 += v3.w;
    }
    for (; e < end; e += G) {
        float4 v = *(const float4*)(tbl + (size_t)ssrc[e] * D + cl * 4);
        x0 += v.x; x1 += v.y; x2 += v.z; x3 += v.w;
    }
    float a0 = x0 + y0 + z0 + w0;
    float a1 = x1 + y1 + z1 + w1;
    float a2 = x2 + y2 + z2 + w2;
    float a3 = x3 + y3 + z3 + w3;
#pragma unroll
    for (int m = LPG; m < 64; m <<= 1) {
        a0 += __shfl_xor(a0, m, 64);
        a1 += __shfl_xor(a1, m, 64);
        a2 += __shfl_xor(a2, m, 64);
        a3 += __shfl_xor(a3, m, 64);
    }
    float wv = inv[wid];
    a0 *= wv; a1 *= wv; a2 *= wv; a3 *= wv;
    if (!SPLIT) {
        if (eg == 0) *(float4*)(outf + (size_t)wid * D + cl * 4) = make_float4(a0, a1, a2, a3);
    } else {
        ushort2 s0 = split_bf(a0), s1 = split_bf(a1), s2 = split_bf(a2), s3 = split_bf(a3);
        if (eg == 0) {
            *(ushort4*)(oh + (size_t)wid * D + cl * 4) = make_ushort4(s0.x, s1.x, s2.x, s3.x);
        } else if (eg == 1) {
            *(ushort4*)(ol + (size_t)wid * D + cl * 4) = make_ushort4(s0.y, s1.y, s2.y, s3.y);
        }
    }
}

// ---------------- operand prep ----------------
__global__ void k_xsplit(const float* __restrict__ in, u16* __restrict__ oh,
                         u16* __restrict__ ol, int n4) {
    int i = blockIdx.x * 256 + threadIdx.x;
    if (i >= n4) return;
    float4 v = ((const float4*)in)[i];
    ushort2 s0 = split_bf(v.x), s1 = split_bf(v.y), s2 = split_bf(v.z), s3 = split_bf(v.w);
    ((ushort4*)oh)[i] = make_ushort4(s0.x, s1.x, s2.x, s3.x);
    ((ushort4*)ol)[i] = make_ushort4(s0.y, s1.y, s2.y, s3.y);
}

// transpose + split all 6 weights in one dispatch (blockIdx.y selects weight).
// Dest pointers may be pre-offset to build concatenated B^T layouts.
__global__ void k_wsplit(const float* __restrict__ W0, const float* __restrict__ W1,
                         const float* __restrict__ W2, const float* __restrict__ W3,
                         const float* __restrict__ W4, const float* __restrict__ W5,
                         u16* o0h, u16* o0l, u16* o1h, u16* o1l, u16* o2h, u16* o2l,
                         u16* o3h, u16* o3l, u16* o4h, u16* o4l, u16* o5h, u16* o5l) {
    const float* W; u16 *oh, *ol; int K, N;
    switch (blockIdx.y) {
        case 0: W = W0; oh = o0h; ol = o0l; K = 128; N = 512; break;
        case 1: W = W1; oh = o1h; ol = o1l; K = 128; N = 512; break;
        case 2: W = W2; oh = o2h; ol = o2l; K = 512; N = 256; break;
        case 3: W = W3; oh = o3h; ol = o3l; K = 512; N = 256; break;
        case 4: W = W4; oh = o4h; ol = o4l; K = 256; N = 64; break;
        default: W = W5; oh = o5h; ol = o5l; K = 256; N = 64; break;
    }
    int i = blockIdx.x * 256 + threadIdx.x;
    if (i >= K * N) return;
    int k = i / N, n = i - k * N;
    ushort2 s = split_bf(W[i]);
    size_t o = (size_t)n * K + k;   // output is W^T [N][K]
    oh[o] = s.x;
    ol[o] = s.y;
}

// ---------------- split-bf16 MFMA GEMM: pipelined, 128x128 tile ----------------
// C = A1@B1 [+ A2@B2] (+bias, act); A@B ~= Ah@Bh + Ah@Bl + Al@Bh.
// Double-buffered LDS (64 KB), one barrier per 32-k iter, async global_load_lds(16B)
// staging with XOR-swizzled k-chunks (fragment ds_read_b128 -> 2-way = conflict-free).
// B pre-transposed [N][K]. K%32==0, N%128==0, M guarded by row clamp.
// Output: cols < colsplit -> out1 (f32 or split planes, stride n1);
//         cols >= colsplit -> out2f (stride n2).
__global__ __launch_bounds__(256) void k_gemm_p(
    int M, int N,
    const u16* __restrict__ A1h, const u16* __restrict__ A1l,
    const u16* __restrict__ B1h, const u16* __restrict__ B1l, int K1,
    const u16* __restrict__ A2h, const u16* __restrict__ A2l,
    const u16* __restrict__ B2h, const u16* __restrict__ B2l, int K2,
    const float* __restrict__ bias, int act, int colsplit,
    float* __restrict__ out1f, u16* __restrict__ out1h, u16* __restrict__ out1l, int n1,
    float* __restrict__ out2f, int n2) {
    __shared__ u16 Ash[2][128 * 32], Asl[2][128 * 32], Bsh[2][128 * 32], Bsl[2][128 * 32];
    const int tid = threadIdx.x;
    const int lane = tid & 63;
    const int w = tid >> 6;
    const int wm = w & 1, wn = w >> 1;
    const int fr = lane & 15;
    const int q = lane >> 4;
    const int brow = blockIdx.y * 128;
    const int bcol = blockIdx.x * 128;

    const int T1 = K1 >> 5, T = T1 + (K2 >> 5);

    // staging coords: chunk c = (w*2+i)*64 + lane; r=c>>2, qq=c&3;
    // global k-chunk = qq ^ ((r>>1)&3)  (XOR swizzle applied on the global side)
    const int c0 = (w * 2 + 0) * 64 + lane;
    const int c1 = (w * 2 + 1) * 64 + lane;
    const int r0 = c0 >> 2, g0 = (c0 & 3) ^ ((r0 >> 1) & 3);
    const int r1 = c1 >> 2, g1 = (c1 & 3) ^ ((r1 >> 1) & 3);
    int ar0 = brow + r0; if (ar0 >= M) ar0 = M - 1;
    int ar1 = brow + r1; if (ar1 >= M) ar1 = M - 1;
    const int br0 = bcol + r0, br1 = bcol + r1;
    const int ub0 = (w * 2 + 0) * 512;   // wave-uniform LDS base (ushorts)
    const int ub1 = (w * 2 + 1) * 512;

    f32x4 acc[4][4] = {};

    auto stage = [&](int kt, int buf) {
        const u16 *Ah, *Al, *Bh, *Bl; int K, k0;
        if (kt < T1) { Ah = A1h; Al = A1l; Bh = B1h; Bl = B1l; K = K1; k0 = kt * 32; }
        else         { Ah = A2h; Al = A2l; Bh = B2h; Bl = B2l; K = K2; k0 = (kt - T1) * 32; }
        size_t ga0 = (size_t)ar0 * K + k0 + g0 * 8;
        size_t ga1 = (size_t)ar1 * K + k0 + g1 * 8;
        size_t gb0 = (size_t)br0 * K + k0 + g0 * 8;
        size_t gb1 = (size_t)br1 * K + k0 + g1 * 8;
        async_load16(Ah + ga0, &Ash[buf][ub0]);
        async_load16(Ah + ga1, &Ash[buf][ub1]);
        async_load16(Al + ga0, &Asl[buf][ub0]);
        async_load16(Al + ga1, &Asl[buf][ub1]);
        async_load16(Bh + gb0, &Bsh[buf][ub0]);
        async_load16(Bh + gb1, &Bsh[buf][ub1]);
        async_load16(Bl + gb0, &Bsl[buf][ub0]);
        async_load16(Bl + gb1, &Bsl[buf][ub1]);
    };

    stage(0, 0);
    for (int kt = 0; kt < T; ++kt) {
        const int p = kt & 1;
        __syncthreads();                 // drains own vmcnt: stage(kt) resident; prior reads done
        if (kt + 1 < T) stage(kt + 1, p ^ 1);   // prefetch in flight during consume
        bf16x8 fah[4], fal[4], fbh[4], fbl[4];
#pragma unroll
        for (int rt = 0; rt < 4; ++rt) {
            int row = wm * 64 + rt * 16 + fr;
            int ad = row * 32 + ((q ^ ((row >> 1) & 3)) * 8);
            fah[rt] = __builtin_bit_cast(bf16x8, *(const uint4*)&Ash[p][ad]);
            fal[rt] = __builtin_bit_cast(bf16x8, *(const uint4*)&Asl[p][ad]);
        }
#pragma unroll
        for (int ct = 0; ct < 4; ++ct) {
            int row = wn * 64 + ct * 16 + fr;
            int ad = row * 32 + ((q ^ ((row >> 1) & 3)) * 8);
            fbh[ct] = __builtin_bit_cast(bf16x8, *(const uint4*)&Bsh[p][ad]);
            fbl[ct] = __builtin_bit_cast(bf16x8, *(const uint4*)&Bsl[p][ad]);
        }
#pragma unroll
        for (int rt = 0; rt < 4; ++rt)
#pragma unroll
            for (int ct = 0; ct < 4; ++ct) {
                acc[rt][ct] = __builtin_amdgcn_mfma_f32_16x16x32_bf16(fah[rt], fbh[ct], acc[rt][ct], 0, 0, 0);
                acc[rt][ct] = __builtin_amdgcn_mfma_f32_16x16x32_bf16(fah[rt], fbl[ct], acc[rt][ct], 0, 0, 0);
                acc[rt][ct] = __builtin_amdgcn_mfma_f32_16x16x32_bf16(fal[rt], fbh[ct], acc[rt][ct], 0, 0, 0);
            }
    }

    // epilogue: frag C/D layout col=lane&15, row=q*4+reg  [m89]
#pragma unroll
    for (int rt = 0; rt < 4; ++rt) {
        int rowb = brow + wm * 64 + rt * 16 + q * 4;
#pragma unroll
        for (int ct = 0; ct < 4; ++ct) {
            int col = bcol + wn * 64 + ct * 16 + fr;
            float b = bias ? bias[col] : 0.f;
#pragma unroll
            for (int r = 0; r < 4; ++r) {
                int row = rowb + r;
                if (row >= M) continue;
                float v = acc[rt][ct][r] + b;
                if (act) v = leaky(v);
                if (col < colsplit) {
                    if (out1f) out1f[(size_t)row * n1 + col] = v;
                    if (out1h) {
                        ushort2 s = split_bf(v);
                        out1h[(size_t)row * n1 + col] = s.x;
                        out1l[(size_t)row * n1 + col] = s.y;
                    }
                } else {
                    out2f[(size_t)row * n2 + (col - colsplit)] = v;
                }
            }
        }
    }
}

// ---------------- h2 epilogue: h2 = leaky(y2 + a2 + b2) -> split planes ----------------
__global__ __launch_bounds__(256) void k_post2(const float* __restrict__ y2,
                                               const float* __restrict__ a2,
                                               const float* __restrict__ b2,
                                               u16* __restrict__ oh, u16* __restrict__ ol) {
    int i = blockIdx.x * 256 + threadIdx.x;       // over N_NODES*256/4
    if (i >= N_NODES * 64) return;
    float4 y = ((const float4*)y2)[i];
    float4 a = ((const float4*)a2)[i];
    const float4 b = *(const float4*)(b2 + (i & 63) * 4);
    float v0 = leaky(y.x + a.x + b.x);
    float v1 = leaky(y.y + a.y + b.y);
    float v2 = leaky(y.z + a.z + b.z);
    float v3 = leaky(y.w + a.w + b.w);
    ushort2 s0 = split_bf(v0), s1 = split_bf(v1), s2 = split_bf(v2), s3 = split_bf(v3);
    ((ushort4*)oh)[i] = make_ushort4(s0.x, s1.x, s2.x, s3.x);
    ((ushort4*)ol)[i] = make_ushort4(s0.y, s1.y, s2.y, s3.y);
}

// ---------------- fused head: h3 = leaky(y3+a3+b3); -> pre_fc -> leaky(fc1) -> fc2 ------
__global__ __launch_bounds__(256) void k_head(const float* __restrict__ y3,
                                              const float* __restrict__ a3,
                                              const float* __restrict__ b3,
                                              const float* __restrict__ Wp, const float* __restrict__ bp,
                                              const float* __restrict__ Wf1, const float* __restrict__ bf1,
                                              const float* __restrict__ Wf2, const float* __restrict__ bf2,
                                              float* __restrict__ out) {
    __shared__ float sWp[64 * 32], sW1[32 * 32], sW2[32 * 2];
    __shared__ float sbp[32], sb1[32], sb2[2], sb3[64];
    int tid = threadIdx.x;
    for (int i = tid; i < 64 * 32; i += 256) sWp[i] = Wp[i];
    for (int i = tid; i < 32 * 32; i += 256) sW1[i] = Wf1[i];
    for (int i = tid; i < 64; i += 256) { sW2[i] = Wf2[i]; sb3[i] = b3[i]; }
    if (tid < 32) { sbp[tid] = bp[tid]; sb1[tid] = bf1[tid]; }
    if (tid < 2) sb2[tid] = bf2[tid];
    __syncthreads();
    int row = blockIdx.x * 256 + tid;
    if (row >= N_NODES) return;
    const float* yr = y3 + (size_t)row * 64;
    const float* ar = a3 + (size_t)row * 64;
    float xr[64];
#pragma unroll
    for (int i = 0; i < 64; ++i) xr[i] = leaky(yr[i] + ar[i] + sb3[i]);
    float h4[32];
    for (int o = 0; o < 32; ++o) {
        float s = sbp[o];
#pragma unroll
        for (int i = 0; i < 64; ++i) s += xr[i] * sWp[i * 32 + o];
        h4[o] = s;
    }
    float h5[32];
    for (int o = 0; o < 32; ++o) {
        float s = sb1[o];
#pragma unroll
        for (int i = 0; i < 32; ++i) s += h4[i] * sW1[i * 32 + o];
        h5[o] = leaky(s);
    }
#pragma unroll
    for (int o = 0; o < 2; ++o) {
        float s = sb2[o];
#pragma unroll
        for (int i = 0; i < 32; ++i) s += h5[i] * sW2[i * 2 + o];
        out[(size_t)row * 2 + o] = s;
    }
}

// ---------------- launch ----------------
extern "C" void kernel_launch(void* const* d_in, const int* in_sizes, int n_in,
                              void* d_out, int out_size, void* d_ws, size_t ws_size,
                              hipStream_t stream) {
    const float* x   = (const float*)d_in[0];
    const int*   ei  = (const int*)d_in[1];
    const float* W1l = (const float*)d_in[5];
    const float* b1  = (const float*)d_in[6];
    const float* W1r = (const float*)d_in[7];
    const float* W2l = (const float*)d_in[8];
    const float* b2  = (const float*)d_in[9];
    const float* W2r = (const float*)d_in[10];
    const float* W3l = (const float*)d_in[11];
    const float* b3  = (const float*)d_in[12];
    const float* W3r = (const float*)d_in[13];
    const float* Wp  = (const float*)d_in[14];
    const float* bp  = (const float*)d_in[15];
    const float* Wf1 = (const float*)d_in[16];
    const float* bf1 = (const float*)d_in[17];
    const float* Wf2 = (const float*)d_in[18];
    const float* bf2 = (const float*)d_in[19];
    float* out = (float*)d_out;
    (void)in_sizes; (void)n_in; (void)out_size; (void)ws_size;

    const int* src = ei;
    const int* dst = ei + N_EDGES;

    char* base = (char*)d_ws;
    size_t off = 0;
    auto alloc = [&](size_t bytes) -> void* {
        void* r = base + off;
        off = (off + bytes + 255) & ~(size_t)255;
        return r;
    };
    const size_t NN = N_NODES;
    int*   cnt    = (int*)alloc(NN * 4);
    int*   offs   = (int*)alloc((NN + 1) * 4);
    int*   cursor = (int*)alloc(NN * 4);
    float* inv    = (float*)alloc(NN * 4);
    int*   ssrc   = (int*)alloc((size_t)N_EDGES * 4);
    // weights: w1 separate (per-phase); w2/w3 concatenated B^T for fused GEMMs
    u16* w1lh = (u16*)alloc(128 * 512 * 2); u16* w1ll = (u16*)alloc(128 * 512 * 2);
    u16* w1rh = (u16*)alloc(128 * 512 * 2); u16* w1rl = (u16*)alloc(128 * 512 * 2);
    u16* w2ch = (u16*)alloc(512 * 512 * 2); u16* w2cl = (u16*)alloc(512 * 512 * 2);  // rows 0-255: w2l^T, 256-511: w2r^T
    u16* w3ch = (u16*)alloc(128 * 256 * 2); u16* w3cl = (u16*)alloc(128 * 256 * 2);  // rows 0-63: w3l^T, 64-127: w3r^T

    // Live-range-aliased regions (~205 MB + ~7 MB misc)
    char* regA = (char*)alloc(NN * 256 * 4);       // xh|xl|axh|axl -> z2 -> h2h|h2l
    char* regB = (char*)alloc(NN * 512 * 2 * 2);   // h1h|h1l -> a2
    char* regD = (char*)alloc(NN * 256 * 4);       // y2 -> z3|y3|a3

    u16* xh  = (u16*)regA;
    u16* xl  = xh + NN * 128;
    u16* axh = xl + NN * 128;
    u16* axl = axh + NN * 128;
    u16* h1h = (u16*)regB;
    u16* h1l = h1h + NN * 512;
    float* z2 = (float*)regA;
    float* a2 = (float*)regB;
    u16* h2h = (u16*)regA;
    u16* h2l = h2h + NN * 256;
    float* y2f = (float*)regD;
    float* z3f = (float*)regD;
    float* y3f = z3f + NN * 64;
    float* a3f = y3f + NN * 64;

    // CSR build (ws re-poisoned every call)
    hipMemsetAsync(cnt, 0, NN * 4, stream);
    k_count<<<(N_EDGES + 255) / 256, 256, 0, stream>>>(dst, cnt);
    k_scan<<<1, 1024, 0, stream>>>(cnt, offs, cursor, inv);
    k_fill<<<(N_EDGES + 255) / 256, 256, 0, stream>>>(src, dst, cursor, ssrc);

    // operand prep
    k_xsplit<<<(N_NODES * 128 / 4 + 255) / 256, 256, 0, stream>>>(x, xh, xl, N_NODES * 128 / 4);
    k_wsplit<<<dim3(512, 6), 256, 0, stream>>>(W1l, W1r, W2l, W2r, W3l, W3r,
        w1lh, w1ll, w1rh, w1rl,
        w2ch, w2cl, w2ch + 256 * 512, w2cl + 256 * 512,
        w3ch, w3cl, w3ch + 64 * 256, w3cl + 64 * 256);

    const int aggGrid = (N_NODES + 3) / 4;
    const int mT = (N_NODES + 127) / 128;

    // layer 1: aggX = S x (split); h1 = leaky(aggX@W1l + x@W1r + b1) (split out)
    k_agg<128, true><<<aggGrid, 256, 0, stream>>>(x, offs, ssrc, inv, nullptr, axh, axl);
    k_gemm_p<<<dim3(4, mT), 256, 0, stream>>>(N_NODES, 512,
        axh, axl, w1lh, w1ll, 128, xh, xl, w1rh, w1rl, 128,
        b1, 1, 512, nullptr, h1h, h1l, 512, nullptr, 0);

    // layer 2 (fused): [z2 | y2] = h1 @ [W2l | W2r]; a2 = S z2; h2 = leaky(y2+a2+b2)
    k_gemm_p<<<dim3(4, mT), 256, 0, stream>>>(N_NODES, 512,
        h1h, h1l, w2ch, w2cl, 512, nullptr, nullptr, nullptr, nullptr, 0,
        nullptr, 0, 256, z2, nullptr, nullptr, 256, y2f, 256);
    k_agg<256, false><<<aggGrid, 256, 0, stream>>>(z2, offs, ssrc, inv, a2, nullptr, nullptr);
    k_post2<<<(N_NODES * 64 + 255) / 256, 256, 0, stream>>>(y2f, a2, b2, h2h, h2l);

    // layer 3 (fused): [z3 | y3] = h2 @ [W3l | W3r]; a3 = S z3; h3 folded into head
    k_gemm_p<<<dim3(1, mT), 256, 0, stream>>>(N_NODES, 128,
        h2h, h2l, w3ch, w3cl, 256, nullptr, nullptr, nullptr, nullptr, 0,
        nullptr, 0, 64, z3f, nullptr, nullptr, 64, y3f, 64);
    k_agg<64, false><<<aggGrid, 256, 0, stream>>>(z3f, offs, ssrc, inv, a3f, nullptr, nullptr);

    // head: h3 = leaky(y3+a3+b3) -> pre_fc -> leaky(fc1) -> fc2
    k_head<<<(N_NODES + 255) / 256, 256, 0, stream>>>(y3f, a3f, b3,
        Wp, bp, Wf1, bf1, Wf2, bf2, out);
}

// Round 6
// 790.725 us; speedup vs baseline: 1.6059x; 1.0182x over previous
//
#include <hip/hip_runtime.h>

#define N_NODES 50000
#define N_EDGES 800000
#define SLOPE 0.15f

typedef unsigned short u16;
typedef __attribute__((ext_vector_type(8))) __bf16 bf16x8;
typedef __attribute__((ext_vector_type(4))) float f32x4;

static __device__ __forceinline__ float leaky(float v) { return v > 0.f ? v : SLOPE * v; }

// split fp32 into hi/lo bf16 pair: v ~= hi + lo, residual ~2^-17 relative
static __device__ __forceinline__ ushort2 split_bf(float v) {
    __bf16 h = (__bf16)v;
    float hf = (float)h;
    __bf16 l = (__bf16)(v - hf);
    ushort2 r;
    r.x = __builtin_bit_cast(unsigned short, h);
    r.y = __builtin_bit_cast(unsigned short, l);
    return r;
}

// async global->LDS 16B: HW writes lane's data to (wave-uniform lds base) + lane*16
static __device__ __forceinline__ void async_load16(const u16* g, u16* l) {
    __builtin_amdgcn_global_load_lds(
        (const __attribute__((address_space(1))) unsigned int*)g,
        (__attribute__((address_space(3))) unsigned int*)l, 16, 0, 0);
}

// ---------------- CSR build ----------------
__global__ void k_count(const int* __restrict__ dst, int* __restrict__ cnt) {
    int e = blockIdx.x * 256 + threadIdx.x;
    if (e < N_EDGES) atomicAdd(&cnt[dst[e]], 1);
}

// single-block scan, wave-shuffle based (4 barriers per 1024-chunk)
__global__ void k_scan(const int* __restrict__ cnt, int* __restrict__ offs,
                       int* __restrict__ cursor, float* __restrict__ inv) {
    __shared__ int wsum[16];
    __shared__ int carry_s;
    int tid = threadIdx.x, lane = tid & 63, wv = tid >> 6;
    if (tid == 0) carry_s = 0;
    __syncthreads();
    for (int base = 0; base < N_NODES; base += 1024) {
        int i = base + tid;
        int orig = (i < N_NODES) ? cnt[i] : 0;
        int v = orig;
#pragma unroll
        for (int d = 1; d < 64; d <<= 1) {
            int t = __shfl_up(v, d, 64);
            if (lane >= d) v += t;
        }
        if (lane == 63) wsum[wv] = v;
        __syncthreads();
        if (wv == 0) {
            int s = (lane < 16) ? wsum[lane] : 0;
#pragma unroll
            for (int d = 1; d < 16; d <<= 1) {
                int t = __shfl_up(s, d, 64);
                if (lane >= d) s += t;
            }
            if (lane < 16) wsum[lane] = s;  // inclusive wave-sums
        }
        __syncthreads();
        int wpre = (wv == 0) ? 0 : wsum[wv - 1];
        int incl = v + wpre + carry_s;
        int excl = incl - orig;
        if (i < N_NODES) {
            offs[i] = excl;
            cursor[i] = excl;
            inv[i] = 1.0f / (float)(orig > 1 ? orig : 1);
        }
        __syncthreads();
        if (tid == 1023) carry_s = incl;
        __syncthreads();
    }
    if (tid == 0) offs[N_NODES] = carry_s;
}

__global__ void k_fill(const int* __restrict__ src, const int* __restrict__ dst,
                       int* __restrict__ cursor, int* __restrict__ ssrc) {
    int e = blockIdx.x * 256 + threadIdx.x;
    if (e < N_EDGES) {
        int pos = atomicAdd(&cursor[dst[e]], 1);
        ssrc[pos] = src[e];
    }
}

// ---------------- mean aggregation ----------------
// one wave per node; G = 256/D edge groups; U-deep masked unroll (no serial tail).
template <int D, int U, bool SPLIT>
__global__ __launch_bounds__(256) void k_agg(const float* __restrict__ tbl,
                                             const int* __restrict__ offs,
                                             const int* __restrict__ ssrc,
                                             const float* __restrict__ inv,
                                             float* __restrict__ outf,
                                             u16* __restrict__ oh, u16* __restrict__ ol) {
    constexpr int G = 256 / D;    // edge groups per wave
    constexpr int LPG = 64 / G;   // lanes per group (= D/4)
    int wid = (blockIdx.x * 256 + threadIdx.x) >> 6;
    if (wid >= N_NODES) return;
    int lane = threadIdx.x & 63;
    int eg = lane / LPG;
    int cl = lane % LPG;
    int beg = offs[wid], end = offs[wid + 1];
    float4 acc[U];
#pragma unroll
    for (int j = 0; j < U; ++j) acc[j] = make_float4(0.f, 0.f, 0.f, 0.f);
    for (int e = beg + eg; e < end; e += U * G) {
        int idx[U]; float msk[U];
#pragma unroll
        for (int j = 0; j < U; ++j) {
            int ee = e + j * G;
            bool ok = ee < end;
            idx[j] = ssrc[ok ? ee : e];
            msk[j] = ok ? 1.f : 0.f;
        }
#pragma unroll
        for (int j = 0; j < U; ++j) {
            const float4 t = *(const float4*)(tbl + (size_t)idx[j] * D + cl * 4);
            acc[j].x = fmaf(t.x, msk[j], acc[j].x);
            acc[j].y = fmaf(t.y, msk[j], acc[j].y);
            acc[j].z = fmaf(t.z, msk[j], acc[j].z);
            acc[j].w = fmaf(t.w, msk[j], acc[j].w);
        }
    }
#pragma unroll
    for (int j = 1; j < U; ++j) {
        acc[0].x += acc[j].x; acc[0].y += acc[j].y;
        acc[0].z += acc[j].z; acc[0].w += acc[j].w;
    }
    float a0 = acc[0].x, a1 = acc[0].y, a2 = acc[0].z, a3 = acc[0].w;
#pragma unroll
    for (int m = LPG; m < 64; m <<= 1) {
        a0 += __shfl_xor(a0, m, 64);
        a1 += __shfl_xor(a1, m, 64);
        a2 += __shfl_xor(a2, m, 64);
        a3 += __shfl_xor(a3, m, 64);
    }
    float wv = inv[wid];
    a0 *= wv; a1 *= wv; a2 *= wv; a3 *= wv;
    if (!SPLIT) {
        if (eg == 0) *(float4*)(outf + (size_t)wid * D + cl * 4) = make_float4(a0, a1, a2, a3);
    } else {
        ushort2 s0 = split_bf(a0), s1 = split_bf(a1), s2 = split_bf(a2), s3 = split_bf(a3);
        if (eg == 0) {
            *(ushort4*)(oh + (size_t)wid * D + cl * 4) = make_ushort4(s0.x, s1.x, s2.x, s3.x);
        } else if (eg == 1) {
            *(ushort4*)(ol + (size_t)wid * D + cl * 4) = make_ushort4(s0.y, s1.y, s2.y, s3.y);
        }
    }
}

// ---------------- operand prep ----------------
__global__ void k_xsplit(const float* __restrict__ in, u16* __restrict__ oh,
                         u16* __restrict__ ol, int n4) {
    int i = blockIdx.x * 256 + threadIdx.x;
    if (i >= n4) return;
    float4 v = ((const float4*)in)[i];
    ushort2 s0 = split_bf(v.x), s1 = split_bf(v.y), s2 = split_bf(v.z), s3 = split_bf(v.w);
    ((ushort4*)oh)[i] = make_ushort4(s0.x, s1.x, s2.x, s3.x);
    ((ushort4*)ol)[i] = make_ushort4(s0.y, s1.y, s2.y, s3.y);
}

// transpose + split all 6 weights in one dispatch (blockIdx.y selects weight).
__global__ void k_wsplit(const float* __restrict__ W0, const float* __restrict__ W1,
                         const float* __restrict__ W2, const float* __restrict__ W3,
                         const float* __restrict__ W4, const float* __restrict__ W5,
                         u16* o0h, u16* o0l, u16* o1h, u16* o1l, u16* o2h, u16* o2l,
                         u16* o3h, u16* o3l, u16* o4h, u16* o4l, u16* o5h, u16* o5l) {
    const float* W; u16 *oh, *ol; int K, N;
    switch (blockIdx.y) {
        case 0: W = W0; oh = o0h; ol = o0l; K = 128; N = 512; break;
        case 1: W = W1; oh = o1h; ol = o1l; K = 128; N = 512; break;
        case 2: W = W2; oh = o2h; ol = o2l; K = 512; N = 256; break;
        case 3: W = W3; oh = o3h; ol = o3l; K = 512; N = 256; break;
        case 4: W = W4; oh = o4h; ol = o4l; K = 256; N = 64; break;
        default: W = W5; oh = o5h; ol = o5l; K = 256; N = 64; break;
    }
    int i = blockIdx.x * 256 + threadIdx.x;
    if (i >= K * N) return;
    int k = i / N, n = i - k * N;
    ushort2 s = split_bf(W[i]);
    size_t o = (size_t)n * K + k;   // output is W^T [N][K]
    oh[o] = s.x;
    ol[o] = s.y;
}

// ---------------- WIDE split-bf16 MFMA GEMM: 128x256 tile, 512 thr, dbuf async ------
// C = A1@B1 [+ A2@B2] (+bias, act); A@B ~= Ah@Bh + Ah@Bl + Al@Bh.
// 8 waves in 2x4; wave computes 64x64 (4x4 16x16x32 frags). 96 KB LDS (2 stages).
// Per 32-k iter: one barrier; prefetch issued post-barrier (depth-1 covers HBM latency
// because per-iter LDS/MFMA work ~1200+ cyc). XOR-swizzled k-chunks (conflict-free).
// B pre-transposed [N][K]. K%32==0, N%256==0, M guarded by row clamp.
// XCD-pair swizzle: 1-D grid, row-tile pairs 8 slots apart share A via same-XCD L2.
__global__ __launch_bounds__(512, 2) void k_gemm_w(
    int M, int N,
    const u16* __restrict__ A1h, const u16* __restrict__ A1l,
    const u16* __restrict__ B1h, const u16* __restrict__ B1l, int K1,
    const u16* __restrict__ A2h, const u16* __restrict__ A2l,
    const u16* __restrict__ B2h, const u16* __restrict__ B2l, int K2,
    const float* __restrict__ bias, int act, int colsplit,
    float* __restrict__ out1f, u16* __restrict__ out1h, u16* __restrict__ out1l, int n1,
    float* __restrict__ out2f, int n2) {
    __shared__ u16 Ash[2][4096], Asl[2][4096], Bsh[2][8192], Bsl[2][8192];
    const int tid = threadIdx.x;
    const int lane = tid & 63;
    const int w = tid >> 6;           // 0..7
    const int wm = w & 1, wn = w >> 1;  // wave grid 2 (rows) x 4 (cols)
    const int fr = lane & 15;
    const int q = lane >> 4;

    const int mT = (M + 127) >> 7;
    // swizzle: L = g*16 + c*8 + x; rowt = g*8 + x; colt = c  (assumes N/256 == 2)
    const int L = blockIdx.x;
    const int rowt = (L >> 4) * 8 + (L & 7);
    const int colt = (L >> 3) & 1;
    if (rowt >= mT) return;
    const int brow = rowt * 128;
    const int bcol = colt * 256;

    const int T1 = K1 >> 5, T = T1 + (K2 >> 5);

    // staging coords (chunk = 16B). A: 512 chunks (1 call), B: 1024 (2 calls) per plane.
    const int cA = w * 64 + lane;
    const int rA = cA >> 2, gA = (cA & 3) ^ ((rA >> 1) & 3);
    int arA = brow + rA; if (arA >= M) arA = M - 1;
    const int cB0 = w * 64 + lane, cB1 = cB0 + 512;
    const int rB0 = cB0 >> 2, gB0 = (cB0 & 3) ^ ((rB0 >> 1) & 3);
    const int rB1 = cB1 >> 2, gB1 = (cB1 & 3) ^ ((rB1 >> 1) & 3);
    const int ubA = w * 512;            // wave-uniform LDS bases (ushorts)
    const int ubB0 = w * 512, ubB1 = w * 512 + 4096;

    f32x4 acc[4][4] = {};

    auto stage = [&](int kt, int buf) {
        const u16 *Ah, *Al, *Bh, *Bl; int K, k0;
        if (kt < T1) { Ah = A1h; Al = A1l; Bh = B1h; Bl = B1l; K = K1; k0 = kt * 32; }
        else         { Ah = A2h; Al = A2l; Bh = B2h; Bl = B2l; K = K2; k0 = (kt - T1) * 32; }
        size_t ga  = (size_t)arA * K + k0 + gA * 8;
        size_t gb0 = (size_t)(bcol + rB0) * K + k0 + gB0 * 8;
        size_t gb1 = (size_t)(bcol + rB1) * K + k0 + gB1 * 8;
        async_load16(Ah + ga,  &Ash[buf][ubA]);
        async_load16(Al + ga,  &Asl[buf][ubA]);
        async_load16(Bh + gb0, &Bsh[buf][ubB0]);
        async_load16(Bh + gb1, &Bsh[buf][ubB1]);
        async_load16(Bl + gb0, &Bsl[buf][ubB0]);
        async_load16(Bl + gb1, &Bsl[buf][ubB1]);
    };

    stage(0, 0);
    for (int kt = 0; kt < T; ++kt) {
        const int p = kt & 1;
        __syncthreads();                        // drain vmcnt: stage(kt) resident
        if (kt + 1 < T) stage(kt + 1, p ^ 1);   // prefetch overlaps consume
        bf16x8 fah[4], fal[4], fbh[4], fbl[4];
#pragma unroll
        for (int rt = 0; rt < 4; ++rt) {
            int row = wm * 64 + rt * 16 + fr;
            int ad = row * 32 + ((q ^ ((row >> 1) & 3)) * 8);
            fah[rt] = __builtin_bit_cast(bf16x8, *(const uint4*)&Ash[p][ad]);
            fal[rt] = __builtin_bit_cast(bf16x8, *(const uint4*)&Asl[p][ad]);
        }
#pragma unroll
        for (int ct = 0; ct < 4; ++ct) {
            int row = wn * 64 + ct * 16 + fr;
            int ad = row * 32 + ((q ^ ((row >> 1) & 3)) * 8);
            fbh[ct] = __builtin_bit_cast(bf16x8, *(const uint4*)&Bsh[p][ad]);
            fbl[ct] = __builtin_bit_cast(bf16x8, *(const uint4*)&Bsl[p][ad]);
        }
#pragma unroll
        for (int rt = 0; rt < 4; ++rt)
#pragma unroll
            for (int ct = 0; ct < 4; ++ct) {
                acc[rt][ct] = __builtin_amdgcn_mfma_f32_16x16x32_bf16(fah[rt], fbh[ct], acc[rt][ct], 0, 0, 0);
                acc[rt][ct] = __builtin_amdgcn_mfma_f32_16x16x32_bf16(fah[rt], fbl[ct], acc[rt][ct], 0, 0, 0);
                acc[rt][ct] = __builtin_amdgcn_mfma_f32_16x16x32_bf16(fal[rt], fbh[ct], acc[rt][ct], 0, 0, 0);
            }
    }

    // epilogue: frag C/D layout col=lane&15, row=q*4+reg  [m89]
#pragma unroll
    for (int rt = 0; rt < 4; ++rt) {
        int rowb = brow + wm * 64 + rt * 16 + q * 4;
#pragma unroll
        for (int ct = 0; ct < 4; ++ct) {
            int col = bcol + wn * 64 + ct * 16 + fr;
            float b = bias ? bias[col] : 0.f;
#pragma unroll
            for (int r = 0; r < 4; ++r) {
                int row = rowb + r;
                if (row >= M) continue;
                float v = acc[rt][ct][r] + b;
                if (act) v = leaky(v);
                if (col < colsplit) {
                    if (out1f) out1f[(size_t)row * n1 + col] = v;
                    if (out1h) {
                        ushort2 s = split_bf(v);
                        out1h[(size_t)row * n1 + col] = s.x;
                        out1l[(size_t)row * n1 + col] = s.y;
                    }
                } else {
                    out2f[(size_t)row * n2 + (col - colsplit)] = v;
                }
            }
        }
    }
}

// ---------------- NARROW split-bf16 MFMA GEMM (N=128, layer-3): 128x128, dbuf --------
__global__ __launch_bounds__(256) void k_gemm_n(
    int M, int N,
    const u16* __restrict__ A1h, const u16* __restrict__ A1l,
    const u16* __restrict__ B1h, const u16* __restrict__ B1l, int K1,
    const float* __restrict__ bias, int act, int colsplit,
    float* __restrict__ out1f, int n1, float* __restrict__ out2f, int n2) {
    __shared__ u16 Ash[2][128 * 32], Asl[2][128 * 32], Bsh[2][128 * 32], Bsl[2][128 * 32];
    const int tid = threadIdx.x;
    const int lane = tid & 63;
    const int w = tid >> 6;
    const int wm = w & 1, wn = w >> 1;
    const int fr = lane & 15;
    const int q = lane >> 4;
    const int brow = blockIdx.y * 128;
    const int bcol = blockIdx.x * 128;

    const int T = K1 >> 5;

    const int c0 = (w * 2 + 0) * 64 + lane;
    const int c1 = (w * 2 + 1) * 64 + lane;
    const int r0 = c0 >> 2, g0 = (c0 & 3) ^ ((r0 >> 1) & 3);
    const int r1 = c1 >> 2, g1 = (c1 & 3) ^ ((r1 >> 1) & 3);
    int ar0 = brow + r0; if (ar0 >= M) ar0 = M - 1;
    int ar1 = brow + r1; if (ar1 >= M) ar1 = M - 1;
    const int br0 = bcol + r0, br1 = bcol + r1;
    const int ub0 = (w * 2 + 0) * 512;
    const int ub1 = (w * 2 + 1) * 512;

    f32x4 acc[4][4] = {};

    auto stage = [&](int kt, int buf) {
        int k0 = kt * 32;
        size_t ga0 = (size_t)ar0 * K1 + k0 + g0 * 8;
        size_t ga1 = (size_t)ar1 * K1 + k0 + g1 * 8;
        size_t gb0 = (size_t)br0 * K1 + k0 + g0 * 8;
        size_t gb1 = (size_t)br1 * K1 + k0 + g1 * 8;
        async_load16(A1h + ga0, &Ash[buf][ub0]);
        async_load16(A1h + ga1, &Ash[buf][ub1]);
        async_load16(A1l + ga0, &Asl[buf][ub0]);
        async_load16(A1l + ga1, &Asl[buf][ub1]);
        async_load16(B1h + gb0, &Bsh[buf][ub0]);
        async_load16(B1h + gb1, &Bsh[buf][ub1]);
        async_load16(B1l + gb0, &Bsl[buf][ub0]);
        async_load16(B1l + gb1, &Bsl[buf][ub1]);
    };

    stage(0, 0);
    for (int kt = 0; kt < T; ++kt) {
        const int p = kt & 1;
        __syncthreads();
        if (kt + 1 < T) stage(kt + 1, p ^ 1);
        bf16x8 fah[4], fal[4], fbh[4], fbl[4];
#pragma unroll
        for (int rt = 0; rt < 4; ++rt) {
            int row = wm * 64 + rt * 16 + fr;
            int ad = row * 32 + ((q ^ ((row >> 1) & 3)) * 8);
            fah[rt] = __builtin_bit_cast(bf16x8, *(const uint4*)&Ash[p][ad]);
            fal[rt] = __builtin_bit_cast(bf16x8, *(const uint4*)&Asl[p][ad]);
        }
#pragma unroll
        for (int ct = 0; ct < 4; ++ct) {
            int row = wn * 64 + ct * 16 + fr;
            int ad = row * 32 + ((q ^ ((row >> 1) & 3)) * 8);
            fbh[ct] = __builtin_bit_cast(bf16x8, *(const uint4*)&Bsh[p][ad]);
            fbl[ct] = __builtin_bit_cast(bf16x8, *(const uint4*)&Bsl[p][ad]);
        }
#pragma unroll
        for (int rt = 0; rt < 4; ++rt)
#pragma unroll
            for (int ct = 0; ct < 4; ++ct) {
                acc[rt][ct] = __builtin_amdgcn_mfma_f32_16x16x32_bf16(fah[rt], fbh[ct], acc[rt][ct], 0, 0, 0);
                acc[rt][ct] = __builtin_amdgcn_mfma_f32_16x16x32_bf16(fah[rt], fbl[ct], acc[rt][ct], 0, 0, 0);
                acc[rt][ct] = __builtin_amdgcn_mfma_f32_16x16x32_bf16(fal[rt], fbh[ct], acc[rt][ct], 0, 0, 0);
            }
    }

#pragma unroll
    for (int rt = 0; rt < 4; ++rt) {
        int rowb = brow + wm * 64 + rt * 16 + q * 4;
#pragma unroll
        for (int ct = 0; ct < 4; ++ct) {
            int col = bcol + wn * 64 + ct * 16 + fr;
            float b = bias ? bias[col] : 0.f;
#pragma unroll
            for (int r = 0; r < 4; ++r) {
                int row = rowb + r;
                if (row >= M) continue;
                float v = acc[rt][ct][r] + b;
                if (act) v = leaky(v);
                if (col < colsplit) out1f[(size_t)row * n1 + col] = v;
                else out2f[(size_t)row * n2 + (col - colsplit)] = v;
            }
        }
    }
}

// ---------------- h2 epilogue: h2 = leaky(y2 + a2 + b2) -> split planes ----------------
__global__ __launch_bounds__(256) void k_post2(const float* __restrict__ y2,
                                               const float* __restrict__ a2,
                                               const float* __restrict__ b2,
                                               u16* __restrict__ oh, u16* __restrict__ ol) {
    int i = blockIdx.x * 256 + threadIdx.x;
    if (i >= N_NODES * 64) return;
    float4 y = ((const float4*)y2)[i];
    float4 a = ((const float4*)a2)[i];
    const float4 b = *(const float4*)(b2 + (i & 63) * 4);
    float v0 = leaky(y.x + a.x + b.x);
    float v1 = leaky(y.y + a.y + b.y);
    float v2 = leaky(y.z + a.z + b.z);
    float v3 = leaky(y.w + a.w + b.w);
    ushort2 s0 = split_bf(v0), s1 = split_bf(v1), s2 = split_bf(v2), s3 = split_bf(v3);
    ((ushort4*)oh)[i] = make_ushort4(s0.x, s1.x, s2.x, s3.x);
    ((ushort4*)ol)[i] = make_ushort4(s0.y, s1.y, s2.y, s3.y);
}

// ---------------- fused head: h3 = leaky(y3+a3+b3); -> pre_fc -> leaky(fc1) -> fc2 ------
__global__ __launch_bounds__(256) void k_head(const float* __restrict__ y3,
                                              const float* __restrict__ a3,
                                              const float* __restrict__ b3,
                                              const float* __restrict__ Wp, const float* __restrict__ bp,
                                              const float* __restrict__ Wf1, const float* __restrict__ bf1,
                                              const float* __restrict__ Wf2, const float* __restrict__ bf2,
                                              float* __restrict__ out) {
    __shared__ float sWp[64 * 32], sW1[32 * 32], sW2[32 * 2];
    __shared__ float sbp[32], sb1[32], sb2[2], sb3[64];
    int tid = threadIdx.x;
    for (int i = tid; i < 64 * 32; i += 256) sWp[i] = Wp[i];
    for (int i = tid; i < 32 * 32; i += 256) sW1[i] = Wf1[i];
    for (int i = tid; i < 64; i += 256) { sW2[i] = Wf2[i]; sb3[i] = b3[i]; }
    if (tid < 32) { sbp[tid] = bp[tid]; sb1[tid] = bf1[tid]; }
    if (tid < 2) sb2[tid] = bf2[tid];
    __syncthreads();
    int row = blockIdx.x * 256 + tid;
    if (row >= N_NODES) return;
    const float4* y4 = (const float4*)(y3 + (size_t)row * 64);
    const float4* a4 = (const float4*)(a3 + (size_t)row * 64);
    float xr[64];
#pragma unroll
    for (int i = 0; i < 16; ++i) {
        float4 yv = y4[i], av = a4[i];
        xr[i * 4 + 0] = leaky(yv.x + av.x + sb3[i * 4 + 0]);
        xr[i * 4 + 1] = leaky(yv.y + av.y + sb3[i * 4 + 1]);
        xr[i * 4 + 2] = leaky(yv.z + av.z + sb3[i * 4 + 2]);
        xr[i * 4 + 3] = leaky(yv.w + av.w + sb3[i * 4 + 3]);
    }
    float h4[32];
    for (int o = 0; o < 32; ++o) {
        float s = sbp[o];
#pragma unroll
        for (int i = 0; i < 64; ++i) s += xr[i] * sWp[i * 32 + o];
        h4[o] = s;
    }
    float h5[32];
    for (int o = 0; o < 32; ++o) {
        float s = sb1[o];
#pragma unroll
        for (int i = 0; i < 32; ++i) s += h4[i] * sW1[i * 32 + o];
        h5[o] = leaky(s);
    }
#pragma unroll
    for (int o = 0; o < 2; ++o) {
        float s = sb2[o];
#pragma unroll
        for (int i = 0; i < 32; ++i) s += h5[i] * sW2[i * 2 + o];
        out[(size_t)row * 2 + o] = s;
    }
}

// ---------------- launch ----------------
extern "C" void kernel_launch(void* const* d_in, const int* in_sizes, int n_in,
                              void* d_out, int out_size, void* d_ws, size_t ws_size,
                              hipStream_t stream) {
    const float* x   = (const float*)d_in[0];
    const int*   ei  = (const int*)d_in[1];
    const float* W1l = (const float*)d_in[5];
    const float* b1  = (const float*)d_in[6];
    const float* W1r = (const float*)d_in[7];
    const float* W2l = (const float*)d_in[8];
    const float* b2  = (const float*)d_in[9];
    const float* W2r = (const float*)d_in[10];
    const float* W3l = (const float*)d_in[11];
    const float* b3  = (const float*)d_in[12];
    const float* W3r = (const float*)d_in[13];
    const float* Wp  = (const float*)d_in[14];
    const float* bp  = (const float*)d_in[15];
    const float* Wf1 = (const float*)d_in[16];
    const float* bf1 = (const float*)d_in[17];
    const float* Wf2 = (const float*)d_in[18];
    const float* bf2 = (const float*)d_in[19];
    float* out = (float*)d_out;
    (void)in_sizes; (void)n_in; (void)out_size; (void)ws_size;

    const int* src = ei;
    const int* dst = ei + N_EDGES;

    char* base = (char*)d_ws;
    size_t off = 0;
    auto alloc = [&](size_t bytes) -> void* {
        void* r = base + off;
        off = (off + bytes + 255) & ~(size_t)255;
        return r;
    };
    const size_t NN = N_NODES;
    int*   cnt    = (int*)alloc(NN * 4);
    int*   offs   = (int*)alloc((NN + 1) * 4);
    int*   cursor = (int*)alloc(NN * 4);
    float* inv    = (float*)alloc(NN * 4);
    int*   ssrc   = (int*)alloc((size_t)N_EDGES * 4);
    // weights: w1 separate (per-phase); w2/w3 concatenated B^T for fused GEMMs
    u16* w1lh = (u16*)alloc(128 * 512 * 2); u16* w1ll = (u16*)alloc(128 * 512 * 2);
    u16* w1rh = (u16*)alloc(128 * 512 * 2); u16* w1rl = (u16*)alloc(128 * 512 * 2);
    u16* w2ch = (u16*)alloc(512 * 512 * 2); u16* w2cl = (u16*)alloc(512 * 512 * 2);
    u16* w3ch = (u16*)alloc(128 * 256 * 2); u16* w3cl = (u16*)alloc(128 * 256 * 2);

    // Live-range-aliased regions (~205 MB)
    char* regA = (char*)alloc(NN * 256 * 4);       // xh|xl|axh|axl -> z2 -> h2h|h2l
    char* regB = (char*)alloc(NN * 512 * 2 * 2);   // h1h|h1l -> a2
    char* regD = (char*)alloc(NN * 256 * 4);       // y2 -> z3|y3|a3

    u16* xh  = (u16*)regA;
    u16* xl  = xh + NN * 128;
    u16* axh = xl + NN * 128;
    u16* axl = axh + NN * 128;
    u16* h1h = (u16*)regB;
    u16* h1l = h1h + NN * 512;
    float* z2 = (float*)regA;
    float* a2 = (float*)regB;
    u16* h2h = (u16*)regA;
    u16* h2l = h2h + NN * 256;
    float* y2f = (float*)regD;
    float* z3f = (float*)regD;
    float* y3f = z3f + NN * 64;
    float* a3f = y3f + NN * 64;

    // CSR build
    hipMemsetAsync(cnt, 0, NN * 4, stream);
    k_count<<<(N_EDGES + 255) / 256, 256, 0, stream>>>(dst, cnt);
    k_scan<<<1, 1024, 0, stream>>>(cnt, offs, cursor, inv);
    k_fill<<<(N_EDGES + 255) / 256, 256, 0, stream>>>(src, dst, cursor, ssrc);

    // operand prep
    k_xsplit<<<(N_NODES * 128 / 4 + 255) / 256, 256, 0, stream>>>(x, xh, xl, N_NODES * 128 / 4);
    k_wsplit<<<dim3(512, 6), 256, 0, stream>>>(W1l, W1r, W2l, W2r, W3l, W3r,
        w1lh, w1ll, w1rh, w1rl,
        w2ch, w2cl, w2ch + 256 * 512, w2cl + 256 * 512,
        w3ch, w3cl, w3ch + 64 * 256, w3cl + 64 * 256);

    const int aggGrid = (N_NODES + 3) / 4;
    const int mT = (N_NODES + 127) / 128;              // 391
    const int wGrid = ((mT + 7) / 8) * 16;             // 784 (2 col tiles, XCD-paired)

    // layer 1: aggX = S x (split); h1 = leaky(aggX@W1l + x@W1r + b1) (split out)
    k_agg<128, 4, true><<<aggGrid, 256, 0, stream>>>(x, offs, ssrc, inv, nullptr, axh, axl);
    k_gemm_w<<<wGrid, 512, 0, stream>>>(N_NODES, 512,
        axh, axl, w1lh, w1ll, 128, xh, xl, w1rh, w1rl, 128,
        b1, 1, 512, nullptr, h1h, h1l, 512, nullptr, 0);

    // layer 2 (fused): [z2 | y2] = h1 @ [W2l | W2r]; a2 = S z2; h2 = leaky(y2+a2+b2)
    k_gemm_w<<<wGrid, 512, 0, stream>>>(N_NODES, 512,
        h1h, h1l, w2ch, w2cl, 512, nullptr, nullptr, nullptr, nullptr, 0,
        nullptr, 0, 256, z2, nullptr, nullptr, 256, y2f, 256);
    k_agg<256, 8, false><<<aggGrid, 256, 0, stream>>>(z2, offs, ssrc, inv, a2, nullptr, nullptr);
    k_post2<<<(N_NODES * 64 + 255) / 256, 256, 0, stream>>>(y2f, a2, b2, h2h, h2l);

    // layer 3 (fused): [z3 | y3] = h2 @ [W3l | W3r]; a3 = S z3; h3 folded into head
    k_gemm_n<<<dim3(1, mT), 256, 0, stream>>>(N_NODES, 128,
        h2h, h2l, w3ch, w3cl, 256, nullptr, 0, 64, z3f, 64, y3f, 64);
    k_agg<64, 4, false><<<aggGrid, 256, 0, stream>>>(z3f, offs, ssrc, inv, a3f, nullptr, nullptr);

    // head: h3 = leaky(y3+a3+b3) -> pre_fc -> leaky(fc1) -> fc2
    k_head<<<(N_NODES + 255) / 256, 256, 0, stream>>>(y3f, a3f, b3,
        Wp, bp, Wf1, bf1, Wf2, bf2, out);
}

// Round 7
// 698.602 us; speedup vs baseline: 1.8177x; 1.1319x over previous
//
#include <hip/hip_runtime.h>

#define N_NODES 50000
#define N_EDGES 800000
#define SLOPE 0.15f

typedef unsigned short u16;
typedef __attribute__((ext_vector_type(8))) __bf16 bf16x8;
typedef __attribute__((ext_vector_type(4))) float f32x4;

static __device__ __forceinline__ float leaky(float v) { return v > 0.f ? v : SLOPE * v; }

// split fp32 into hi/lo bf16 pair: v ~= hi + lo, residual ~2^-17 relative
static __device__ __forceinline__ ushort2 split_bf(float v) {
    __bf16 h = (__bf16)v;
    float hf = (float)h;
    __bf16 l = (__bf16)(v - hf);
    ushort2 r;
    r.x = __builtin_bit_cast(unsigned short, h);
    r.y = __builtin_bit_cast(unsigned short, l);
    return r;
}

// async global->LDS 16B: HW writes lane's data to (wave-uniform lds base) + lane*16
static __device__ __forceinline__ void async_load16(const u16* g, u16* l) {
    __builtin_amdgcn_global_load_lds(
        (const __attribute__((address_space(1))) unsigned int*)g,
        (__attribute__((address_space(3))) unsigned int*)l, 16, 0, 0);
}

// ---------------- CSR build ----------------
__global__ void k_count(const int* __restrict__ dst, int* __restrict__ cnt) {
    int e = blockIdx.x * 256 + threadIdx.x;
    if (e < N_EDGES) atomicAdd(&cnt[dst[e]], 1);
}

// single-block scan, wave-shuffle based (4 barriers per 1024-chunk)
__global__ void k_scan(const int* __restrict__ cnt, int* __restrict__ offs,
                       int* __restrict__ cursor, float* __restrict__ inv) {
    __shared__ int wsum[16];
    __shared__ int carry_s;
    int tid = threadIdx.x, lane = tid & 63, wv = tid >> 6;
    if (tid == 0) carry_s = 0;
    __syncthreads();
    for (int base = 0; base < N_NODES; base += 1024) {
        int i = base + tid;
        int orig = (i < N_NODES) ? cnt[i] : 0;
        int v = orig;
#pragma unroll
        for (int d = 1; d < 64; d <<= 1) {
            int t = __shfl_up(v, d, 64);
            if (lane >= d) v += t;
        }
        if (lane == 63) wsum[wv] = v;
        __syncthreads();
        if (wv == 0) {
            int s = (lane < 16) ? wsum[lane] : 0;
#pragma unroll
            for (int d = 1; d < 16; d <<= 1) {
                int t = __shfl_up(s, d, 64);
                if (lane >= d) s += t;
            }
            if (lane < 16) wsum[lane] = s;  // inclusive wave-sums
        }
        __syncthreads();
        int wpre = (wv == 0) ? 0 : wsum[wv - 1];
        int incl = v + wpre + carry_s;
        int excl = incl - orig;
        if (i < N_NODES) {
            offs[i] = excl;
            cursor[i] = excl;
            inv[i] = 1.0f / (float)(orig > 1 ? orig : 1);
        }
        __syncthreads();
        if (tid == 1023) carry_s = incl;
        __syncthreads();
    }
    if (tid == 0) offs[N_NODES] = carry_s;
}

__global__ void k_fill(const int* __restrict__ src, const int* __restrict__ dst,
                       int* __restrict__ cursor, int* __restrict__ ssrc) {
    int e = blockIdx.x * 256 + threadIdx.x;
    if (e < N_EDGES) {
        int pos = atomicAdd(&cursor[dst[e]], 1);
        ssrc[pos] = src[e];
    }
}

// ---------------- mean aggregation ----------------
// one wave per node; G = 256/D edge groups; U-deep masked unroll (no serial tail).
template <int D, int U, bool SPLIT>
__global__ __launch_bounds__(256) void k_agg(const float* __restrict__ tbl,
                                             const int* __restrict__ offs,
                                             const int* __restrict__ ssrc,
                                             const float* __restrict__ inv,
                                             float* __restrict__ outf,
                                             u16* __restrict__ oh, u16* __restrict__ ol) {
    constexpr int G = 256 / D;    // edge groups per wave
    constexpr int LPG = 64 / G;   // lanes per group (= D/4)
    int wid = (blockIdx.x * 256 + threadIdx.x) >> 6;
    if (wid >= N_NODES) return;
    int lane = threadIdx.x & 63;
    int eg = lane / LPG;
    int cl = lane % LPG;
    int beg = offs[wid], end = offs[wid + 1];
    float4 acc[U];
#pragma unroll
    for (int j = 0; j < U; ++j) acc[j] = make_float4(0.f, 0.f, 0.f, 0.f);
    for (int e = beg + eg; e < end; e += U * G) {
        int idx[U]; float msk[U];
#pragma unroll
        for (int j = 0; j < U; ++j) {
            int ee = e + j * G;
            bool ok = ee < end;
            idx[j] = ssrc[ok ? ee : e];
            msk[j] = ok ? 1.f : 0.f;
        }
#pragma unroll
        for (int j = 0; j < U; ++j) {
            const float4 t = *(const float4*)(tbl + (size_t)idx[j] * D + cl * 4);
            acc[j].x = fmaf(t.x, msk[j], acc[j].x);
            acc[j].y = fmaf(t.y, msk[j], acc[j].y);
            acc[j].z = fmaf(t.z, msk[j], acc[j].z);
            acc[j].w = fmaf(t.w, msk[j], acc[j].w);
        }
    }
#pragma unroll
    for (int j = 1; j < U; ++j) {
        acc[0].x += acc[j].x; acc[0].y += acc[j].y;
        acc[0].z += acc[j].z; acc[0].w += acc[j].w;
    }
    float a0 = acc[0].x, a1 = acc[0].y, a2 = acc[0].z, a3 = acc[0].w;
#pragma unroll
    for (int m = LPG; m < 64; m <<= 1) {
        a0 += __shfl_xor(a0, m, 64);
        a1 += __shfl_xor(a1, m, 64);
        a2 += __shfl_xor(a2, m, 64);
        a3 += __shfl_xor(a3, m, 64);
    }
    float wv = inv[wid];
    a0 *= wv; a1 *= wv; a2 *= wv; a3 *= wv;
    if (!SPLIT) {
        if (eg == 0) *(float4*)(outf + (size_t)wid * D + cl * 4) = make_float4(a0, a1, a2, a3);
    } else {
        ushort2 s0 = split_bf(a0), s1 = split_bf(a1), s2 = split_bf(a2), s3 = split_bf(a3);
        if (eg == 0) {
            *(ushort4*)(oh + (size_t)wid * D + cl * 4) = make_ushort4(s0.x, s1.x, s2.x, s3.x);
        } else if (eg == 1) {
            *(ushort4*)(ol + (size_t)wid * D + cl * 4) = make_ushort4(s0.y, s1.y, s2.y, s3.y);
        }
    }
}

// ---------------- operand prep ----------------
__global__ void k_xsplit(const float* __restrict__ in, u16* __restrict__ oh,
                         u16* __restrict__ ol, int n4) {
    int i = blockIdx.x * 256 + threadIdx.x;
    if (i >= n4) return;
    float4 v = ((const float4*)in)[i];
    ushort2 s0 = split_bf(v.x), s1 = split_bf(v.y), s2 = split_bf(v.z), s3 = split_bf(v.w);
    ((ushort4*)oh)[i] = make_ushort4(s0.x, s1.x, s2.x, s3.x);
    ((ushort4*)ol)[i] = make_ushort4(s0.y, s1.y, s2.y, s3.y);
}

// transpose + split all 6 weights in one dispatch (blockIdx.y selects weight).
__global__ void k_wsplit(const float* __restrict__ W0, const float* __restrict__ W1,
                         const float* __restrict__ W2, const float* __restrict__ W3,
                         const float* __restrict__ W4, const float* __restrict__ W5,
                         u16* o0h, u16* o0l, u16* o1h, u16* o1l, u16* o2h, u16* o2l,
                         u16* o3h, u16* o3l, u16* o4h, u16* o4l, u16* o5h, u16* o5l) {
    const float* W; u16 *oh, *ol; int K, N;
    switch (blockIdx.y) {
        case 0: W = W0; oh = o0h; ol = o0l; K = 128; N = 512; break;
        case 1: W = W1; oh = o1h; ol = o1l; K = 128; N = 512; break;
        case 2: W = W2; oh = o2h; ol = o2l; K = 512; N = 256; break;
        case 3: W = W3; oh = o3h; ol = o3l; K = 512; N = 256; break;
        case 4: W = W4; oh = o4h; ol = o4l; K = 256; N = 64; break;
        default: W = W5; oh = o5h; ol = o5l; K = 256; N = 64; break;
    }
    int i = blockIdx.x * 256 + threadIdx.x;
    if (i >= K * N) return;
    int k = i / N, n = i - k * N;
    ushort2 s = split_bf(W[i]);
    size_t o = (size_t)n * K + k;   // output is W^T [N][K]
    oh[o] = s.x;
    ol[o] = s.y;
}

// ---------------- split-bf16 MFMA GEMM: 128x128 tile, single-buffer, 4 blocks/CU ------
// C = A1@B1 [+ A2@B2] (+bias, act); A@B ~= Ah@Bh + Ah@Bl + Al@Bh.
// 256 thr = 4 waves (2x2); wave computes 64x64 (4x4 16x16x32 frags).
// Single-staged 32 KB LDS -> 4 blocks/CU; latency hidden by cross-block overlap
// (m114). XOR-swizzled k-chunks -> conflict-free ds_read_b128.
// XCD swizzle: groups of 8*nct linear blocks = 8 row-tiles x nct col-tiles such that
// all col-tiles of a row-tile share an XCD (A L2 reuse).
// B pre-transposed [N][K]. K%32==0, cols = nct*128, M guarded by row clamp.
__global__ __launch_bounds__(256, 4) void k_gemm_s(
    int M, int nct,
    const u16* __restrict__ A1h, const u16* __restrict__ A1l,
    const u16* __restrict__ B1h, const u16* __restrict__ B1l, int K1,
    const u16* __restrict__ A2h, const u16* __restrict__ A2l,
    const u16* __restrict__ B2h, const u16* __restrict__ B2l, int K2,
    const float* __restrict__ bias, int act, int colsplit,
    float* __restrict__ out1f, u16* __restrict__ out1h, u16* __restrict__ out1l, int n1,
    float* __restrict__ out2f, int n2) {
    __shared__ u16 Ash[4096], Asl[4096], Bsh[4096], Bsl[4096];
    const int tid = threadIdx.x;
    const int lane = tid & 63;
    const int w = tid >> 6;
    const int wm = w & 1, wn = w >> 1;
    const int fr = lane & 15;
    const int q = lane >> 4;

    const int mT = (M + 127) >> 7;
    const int lin = blockIdx.x;
    const int grp = lin / (8 * nct);
    const int idx = lin - grp * (8 * nct);
    const int ct = idx >> 3;          // col-tile
    const int s8 = idx & 7;           // XCD slot
    const int rowt = grp * 8 + s8;
    if (rowt >= mT) return;
    const int brow = rowt * 128;
    const int bcol = ct * 128;

    const int T1 = K1 >> 5, T = T1 + (K2 >> 5);

    // staging coords: 512 16B-chunks per plane; 2 per thread
    const int c0 = (w * 2 + 0) * 64 + lane;
    const int c1 = (w * 2 + 1) * 64 + lane;
    const int r0 = c0 >> 2, g0 = (c0 & 3) ^ ((r0 >> 1) & 3);
    const int r1 = c1 >> 2, g1 = (c1 & 3) ^ ((r1 >> 1) & 3);
    int ar0 = brow + r0; if (ar0 >= M) ar0 = M - 1;
    int ar1 = brow + r1; if (ar1 >= M) ar1 = M - 1;
    const int br0 = bcol + r0, br1 = bcol + r1;
    const int ub0 = (w * 2 + 0) * 512;   // wave-uniform LDS bases (ushorts)
    const int ub1 = (w * 2 + 1) * 512;

    f32x4 acc[4][4] = {};

    for (int kt = 0; kt < T; ++kt) {
        const u16 *Ah, *Al, *Bh, *Bl; int K, k0;
        if (kt < T1) { Ah = A1h; Al = A1l; Bh = B1h; Bl = B1l; K = K1; k0 = kt * 32; }
        else         { Ah = A2h; Al = A2l; Bh = B2h; Bl = B2l; K = K2; k0 = (kt - T1) * 32; }
        __syncthreads();   // all waves done reading previous slice
        {
            size_t ga0 = (size_t)ar0 * K + k0 + g0 * 8;
            size_t ga1 = (size_t)ar1 * K + k0 + g1 * 8;
            size_t gb0 = (size_t)br0 * K + k0 + g0 * 8;
            size_t gb1 = (size_t)br1 * K + k0 + g1 * 8;
            async_load16(Ah + ga0, &Ash[ub0]);
            async_load16(Ah + ga1, &Ash[ub1]);
            async_load16(Al + ga0, &Asl[ub0]);
            async_load16(Al + ga1, &Asl[ub1]);
            async_load16(Bh + gb0, &Bsh[ub0]);
            async_load16(Bh + gb1, &Bsh[ub1]);
            async_load16(Bl + gb0, &Bsl[ub0]);
            async_load16(Bl + gb1, &Bsl[ub1]);
        }
        __syncthreads();   // vmcnt drain + stage visible
        bf16x8 fah[4], fal[4], fbh[4], fbl[4];
#pragma unroll
        for (int rt = 0; rt < 4; ++rt) {
            int row = wm * 64 + rt * 16 + fr;
            int ad = row * 32 + ((q ^ ((row >> 1) & 3)) * 8);
            fah[rt] = __builtin_bit_cast(bf16x8, *(const uint4*)&Ash[ad]);
            fal[rt] = __builtin_bit_cast(bf16x8, *(const uint4*)&Asl[ad]);
        }
#pragma unroll
        for (int ctf = 0; ctf < 4; ++ctf) {
            int row = wn * 64 + ctf * 16 + fr;
            int ad = row * 32 + ((q ^ ((row >> 1) & 3)) * 8);
            fbh[ctf] = __builtin_bit_cast(bf16x8, *(const uint4*)&Bsh[ad]);
            fbl[ctf] = __builtin_bit_cast(bf16x8, *(const uint4*)&Bsl[ad]);
        }
#pragma unroll
        for (int rt = 0; rt < 4; ++rt)
#pragma unroll
            for (int ctf = 0; ctf < 4; ++ctf) {
                acc[rt][ctf] = __builtin_amdgcn_mfma_f32_16x16x32_bf16(fah[rt], fbh[ctf], acc[rt][ctf], 0, 0, 0);
                acc[rt][ctf] = __builtin_amdgcn_mfma_f32_16x16x32_bf16(fah[rt], fbl[ctf], acc[rt][ctf], 0, 0, 0);
                acc[rt][ctf] = __builtin_amdgcn_mfma_f32_16x16x32_bf16(fal[rt], fbh[ctf], acc[rt][ctf], 0, 0, 0);
            }
    }

    // epilogue: frag C/D layout col=lane&15, row=q*4+reg  [m89]
#pragma unroll
    for (int rt = 0; rt < 4; ++rt) {
        int rowb = brow + wm * 64 + rt * 16 + q * 4;
#pragma unroll
        for (int ctf = 0; ctf < 4; ++ctf) {
            int col = bcol + wn * 64 + ctf * 16 + fr;
            float b = bias ? bias[col] : 0.f;
#pragma unroll
            for (int r = 0; r < 4; ++r) {
                int row = rowb + r;
                if (row >= M) continue;
                float v = acc[rt][ctf][r] + b;
                if (act) v = leaky(v);
                if (col < colsplit) {
                    if (out1f) out1f[(size_t)row * n1 + col] = v;
                    if (out1h) {
                        ushort2 s = split_bf(v);
                        out1h[(size_t)row * n1 + col] = s.x;
                        out1l[(size_t)row * n1 + col] = s.y;
                    }
                } else {
                    out2f[(size_t)row * n2 + (col - colsplit)] = v;
                }
            }
        }
    }
}

// ---------------- h2 epilogue: h2 = leaky(y2 + a2 + b2) -> split planes ----------------
__global__ __launch_bounds__(256) void k_post2(const float* __restrict__ y2,
                                               const float* __restrict__ a2,
                                               const float* __restrict__ b2,
                                               u16* __restrict__ oh, u16* __restrict__ ol) {
    int i = blockIdx.x * 256 + threadIdx.x;
    if (i >= N_NODES * 64) return;
    float4 y = ((const float4*)y2)[i];
    float4 a = ((const float4*)a2)[i];
    const float4 b = *(const float4*)(b2 + (i & 63) * 4);
    float v0 = leaky(y.x + a.x + b.x);
    float v1 = leaky(y.y + a.y + b.y);
    float v2 = leaky(y.z + a.z + b.z);
    float v3 = leaky(y.w + a.w + b.w);
    ushort2 s0 = split_bf(v0), s1 = split_bf(v1), s2 = split_bf(v2), s3 = split_bf(v3);
    ((ushort4*)oh)[i] = make_ushort4(s0.x, s1.x, s2.x, s3.x);
    ((ushort4*)ol)[i] = make_ushort4(s0.y, s1.y, s2.y, s3.y);
}

// ---------------- fused head: h3 = leaky(y3+a3+b3); -> pre_fc -> leaky(fc1) -> fc2 ------
__global__ __launch_bounds__(256) void k_head(const float* __restrict__ y3,
                                              const float* __restrict__ a3,
                                              const float* __restrict__ b3,
                                              const float* __restrict__ Wp, const float* __restrict__ bp,
                                              const float* __restrict__ Wf1, const float* __restrict__ bf1,
                                              const float* __restrict__ Wf2, const float* __restrict__ bf2,
                                              float* __restrict__ out) {
    __shared__ float sWp[64 * 32], sW1[32 * 32], sW2[32 * 2];
    __shared__ float sbp[32], sb1[32], sb2[2], sb3[64];
    int tid = threadIdx.x;
    for (int i = tid; i < 64 * 32; i += 256) sWp[i] = Wp[i];
    for (int i = tid; i < 32 * 32; i += 256) sW1[i] = Wf1[i];
    for (int i = tid; i < 64; i += 256) { sW2[i] = Wf2[i]; sb3[i] = b3[i]; }
    if (tid < 32) { sbp[tid] = bp[tid]; sb1[tid] = bf1[tid]; }
    if (tid < 2) sb2[tid] = bf2[tid];
    __syncthreads();
    int row = blockIdx.x * 256 + tid;
    if (row >= N_NODES) return;
    const float4* y4 = (const float4*)(y3 + (size_t)row * 64);
    const float4* a4 = (const float4*)(a3 + (size_t)row * 64);
    float xr[64];
#pragma unroll
    for (int i = 0; i < 16; ++i) {
        float4 yv = y4[i], av = a4[i];
        xr[i * 4 + 0] = leaky(yv.x + av.x + sb3[i * 4 + 0]);
        xr[i * 4 + 1] = leaky(yv.y + av.y + sb3[i * 4 + 1]);
        xr[i * 4 + 2] = leaky(yv.z + av.z + sb3[i * 4 + 2]);
        xr[i * 4 + 3] = leaky(yv.w + av.w + sb3[i * 4 + 3]);
    }
    float h4[32];
    for (int o = 0; o < 32; ++o) {
        float s = sbp[o];
#pragma unroll
        for (int i = 0; i < 64; ++i) s += xr[i] * sWp[i * 32 + o];
        h4[o] = s;
    }
    float h5[32];
    for (int o = 0; o < 32; ++o) {
        float s = sb1[o];
#pragma unroll
        for (int i = 0; i < 32; ++i) s += h4[i] * sW1[i * 32 + o];
        h5[o] = leaky(s);
    }
#pragma unroll
    for (int o = 0; o < 2; ++o) {
        float s = sb2[o];
#pragma unroll
        for (int i = 0; i < 32; ++i) s += h5[i] * sW2[i * 2 + o];
        out[(size_t)row * 2 + o] = s;
    }
}

// ---------------- launch ----------------
extern "C" void kernel_launch(void* const* d_in, const int* in_sizes, int n_in,
                              void* d_out, int out_size, void* d_ws, size_t ws_size,
                              hipStream_t stream) {
    const float* x   = (const float*)d_in[0];
    const int*   ei  = (const int*)d_in[1];
    const float* W1l = (const float*)d_in[5];
    const float* b1  = (const float*)d_in[6];
    const float* W1r = (const float*)d_in[7];
    const float* W2l = (const float*)d_in[8];
    const float* b2  = (const float*)d_in[9];
    const float* W2r = (const float*)d_in[10];
    const float* W3l = (const float*)d_in[11];
    const float* b3  = (const float*)d_in[12];
    const float* W3r = (const float*)d_in[13];
    const float* Wp  = (const float*)d_in[14];
    const float* bp  = (const float*)d_in[15];
    const float* Wf1 = (const float*)d_in[16];
    const float* bf1 = (const float*)d_in[17];
    const float* Wf2 = (const float*)d_in[18];
    const float* bf2 = (const float*)d_in[19];
    float* out = (float*)d_out;
    (void)in_sizes; (void)n_in; (void)out_size; (void)ws_size;

    const int* src = ei;
    const int* dst = ei + N_EDGES;

    char* base = (char*)d_ws;
    size_t off = 0;
    auto alloc = [&](size_t bytes) -> void* {
        void* r = base + off;
        off = (off + bytes + 255) & ~(size_t)255;
        return r;
    };
    const size_t NN = N_NODES;
    int*   cnt    = (int*)alloc(NN * 4);
    int*   offs   = (int*)alloc((NN + 1) * 4);
    int*   cursor = (int*)alloc(NN * 4);
    float* inv    = (float*)alloc(NN * 4);
    int*   ssrc   = (int*)alloc((size_t)N_EDGES * 4);
    // weights: w1 separate (per-phase); w2/w3 concatenated B^T for fused GEMMs
    u16* w1lh = (u16*)alloc(128 * 512 * 2); u16* w1ll = (u16*)alloc(128 * 512 * 2);
    u16* w1rh = (u16*)alloc(128 * 512 * 2); u16* w1rl = (u16*)alloc(128 * 512 * 2);
    u16* w2ch = (u16*)alloc(512 * 512 * 2); u16* w2cl = (u16*)alloc(512 * 512 * 2);
    u16* w3ch = (u16*)alloc(128 * 256 * 2); u16* w3cl = (u16*)alloc(128 * 256 * 2);

    // Live-range-aliased regions (~205 MB)
    char* regA = (char*)alloc(NN * 256 * 4);       // xh|xl|axh|axl -> z2 -> h2h|h2l
    char* regB = (char*)alloc(NN * 512 * 2 * 2);   // h1h|h1l -> a2
    char* regD = (char*)alloc(NN * 256 * 4);       // y2 -> z3|y3|a3

    u16* xh  = (u16*)regA;
    u16* xl  = xh + NN * 128;
    u16* axh = xl + NN * 128;
    u16* axl = axh + NN * 128;
    u16* h1h = (u16*)regB;
    u16* h1l = h1h + NN * 512;
    float* z2 = (float*)regA;
    float* a2 = (float*)regB;
    u16* h2h = (u16*)regA;
    u16* h2l = h2h + NN * 256;
    float* y2f = (float*)regD;
    float* z3f = (float*)regD;
    float* y3f = z3f + NN * 64;
    float* a3f = y3f + NN * 64;

    // CSR build
    hipMemsetAsync(cnt, 0, NN * 4, stream);
    k_count<<<(N_EDGES + 255) / 256, 256, 0, stream>>>(dst, cnt);
    k_scan<<<1, 1024, 0, stream>>>(cnt, offs, cursor, inv);
    k_fill<<<(N_EDGES + 255) / 256, 256, 0, stream>>>(src, dst, cursor, ssrc);

    // operand prep
    k_xsplit<<<(N_NODES * 128 / 4 + 255) / 256, 256, 0, stream>>>(x, xh, xl, N_NODES * 128 / 4);
    k_wsplit<<<dim3(512, 6), 256, 0, stream>>>(W1l, W1r, W2l, W2r, W3l, W3r,
        w1lh, w1ll, w1rh, w1rl,
        w2ch, w2cl, w2ch + 256 * 512, w2cl + 256 * 512,
        w3ch, w3cl, w3ch + 64 * 256, w3cl + 64 * 256);

    const int aggGrid = (N_NODES + 3) / 4;
    const int mT = (N_NODES + 127) / 128;              // 391
    const int grid4 = ((mT + 7) / 8) * 32;             // nct=4 -> 1600
    const int grid1 = ((mT + 7) / 8) * 8;              // nct=1 -> 400

    // layer 1: aggX = S x (split); h1 = leaky(aggX@W1l + x@W1r + b1) (split out)
    k_agg<128, 4, true><<<aggGrid, 256, 0, stream>>>(x, offs, ssrc, inv, nullptr, axh, axl);
    k_gemm_s<<<grid4, 256, 0, stream>>>(N_NODES, 4,
        axh, axl, w1lh, w1ll, 128, xh, xl, w1rh, w1rl, 128,
        b1, 1, 512, nullptr, h1h, h1l, 512, nullptr, 0);

    // layer 2 (fused): [z2 | y2] = h1 @ [W2l | W2r]; a2 = S z2; h2 = leaky(y2+a2+b2)
    k_gemm_s<<<grid4, 256, 0, stream>>>(N_NODES, 4,
        h1h, h1l, w2ch, w2cl, 512, nullptr, nullptr, nullptr, nullptr, 0,
        nullptr, 0, 256, z2, nullptr, nullptr, 256, y2f, 256);
    k_agg<256, 8, false><<<aggGrid, 256, 0, stream>>>(z2, offs, ssrc, inv, a2, nullptr, nullptr);
    k_post2<<<(N_NODES * 64 + 255) / 256, 256, 0, stream>>>(y2f, a2, b2, h2h, h2l);

    // layer 3 (fused): [z3 | y3] = h2 @ [W3l | W3r]; a3 = S z3; h3 folded into head
    k_gemm_s<<<grid1, 256, 0, stream>>>(N_NODES, 1,
        h2h, h2l, w3ch, w3cl, 256, nullptr, nullptr, nullptr, nullptr, 0,
        nullptr, 0, 64, z3f, nullptr, nullptr, 64, y3f, 64);
    k_agg<64, 4, false><<<aggGrid, 256, 0, stream>>>(z3f, offs, ssrc, inv, a3f, nullptr, nullptr);

    // head: h3 = leaky(y3+a3+b3) -> pre_fc -> leaky(fc1) -> fc2
    k_head<<<(N_NODES + 255) / 256, 256, 0, stream>>>(y3f, a3f, b3,
        Wp, bp, Wf1, bf1, Wf2, bf2, out);
}

// Round 8
// 678.760 us; speedup vs baseline: 1.8708x; 1.0292x over previous
//
#include <hip/hip_runtime.h>

#define N_NODES 50000
#define N_EDGES 800000
#define SLOPE 0.15f

typedef unsigned short u16;
typedef __attribute__((ext_vector_type(8))) __bf16 bf16x8;
typedef __attribute__((ext_vector_type(4))) float f32x4;

static __device__ __forceinline__ float leaky(float v) { return v > 0.f ? v : SLOPE * v; }

// split fp32 into hi/lo bf16 pair: v ~= hi + lo, residual ~2^-17 relative
static __device__ __forceinline__ ushort2 split_bf(float v) {
    __bf16 h = (__bf16)v;
    float hf = (float)h;
    __bf16 l = (__bf16)(v - hf);
    ushort2 r;
    r.x = __builtin_bit_cast(unsigned short, h);
    r.y = __builtin_bit_cast(unsigned short, l);
    return r;
}

// async global->LDS 16B: HW writes lane's data to (wave-uniform lds base) + lane*16
static __device__ __forceinline__ void async_load16(const u16* g, u16* l) {
    __builtin_amdgcn_global_load_lds(
        (const __attribute__((address_space(1))) unsigned int*)g,
        (__attribute__((address_space(3))) unsigned int*)l, 16, 0, 0);
}

// ---------------- CSR build ----------------
__global__ void k_count(const int* __restrict__ dst, int* __restrict__ cnt) {
    int e = blockIdx.x * 256 + threadIdx.x;
    if (e < N_EDGES) atomicAdd(&cnt[dst[e]], 1);
}

// multi-block scan, stage 1: per-1024-block local exclusive scan + block total
__global__ __launch_bounds__(1024) void k_scan1(const int* __restrict__ cnt,
                                                int* __restrict__ offs,
                                                int* __restrict__ bsum) {
    __shared__ int wsum[16];
    int tid = threadIdx.x, lane = tid & 63, wv = tid >> 6;
    int i = blockIdx.x * 1024 + tid;
    int orig = (i < N_NODES) ? cnt[i] : 0;
    int v = orig;
#pragma unroll
    for (int d = 1; d < 64; d <<= 1) {
        int t = __shfl_up(v, d, 64);
        if (lane >= d) v += t;
    }
    if (lane == 63) wsum[wv] = v;
    __syncthreads();
    if (wv == 0) {
        int s = (lane < 16) ? wsum[lane] : 0;
#pragma unroll
        for (int d = 1; d < 16; d <<= 1) {
            int t = __shfl_up(s, d, 64);
            if (lane >= d) s += t;
        }
        if (lane < 16) wsum[lane] = s;          // inclusive wave sums
        if (lane == 15) bsum[blockIdx.x] = s;   // block total
    }
    __syncthreads();
    int wpre = (wv == 0) ? 0 : wsum[wv - 1];
    if (i < N_NODES) offs[i] = v + wpre - orig; // local exclusive
}

// stage 2: one wave scans the (<=64) block sums -> exclusive
__global__ void k_scan2(int* __restrict__ bsum, int nb) {
    int lane = threadIdx.x;
    int v = (lane < nb) ? bsum[lane] : 0;
    int s = v;
#pragma unroll
    for (int d = 1; d < 64; d <<= 1) {
        int t = __shfl_up(s, d, 64);
        if (lane >= d) s += t;
    }
    if (lane < nb) bsum[lane] = s - v;
}

// stage 3: add block offsets; emit cursor + inv; offs[N] is the constant edge count
__global__ void k_scan3(const int* __restrict__ cnt, int* __restrict__ offs,
                        int* __restrict__ cursor, float* __restrict__ inv,
                        const int* __restrict__ bsum) {
    int i = blockIdx.x * 256 + threadIdx.x;
    if (i >= N_NODES) return;
    int c = cnt[i];
    int o = offs[i] + bsum[i >> 10];
    offs[i] = o;
    cursor[i] = o;
    inv[i] = 1.0f / (float)(c > 1 ? c : 1);
    if (i == 0) offs[N_NODES] = N_EDGES;
}

__global__ void k_fill(const int* __restrict__ src, const int* __restrict__ dst,
                       int* __restrict__ cursor, int* __restrict__ ssrc) {
    int e = blockIdx.x * 256 + threadIdx.x;
    if (e < N_EDGES) {
        int pos = atomicAdd(&cursor[dst[e]], 1);
        ssrc[pos] = src[e];
    }
}

// ---------------- mean aggregation (column-split) ----------------
// One wave handles D columns of one node (blockIdx.y picks the column chunk of a
// STRIDE-wide table). G = 256/D edges per iteration; U-deep masked unroll.
template <int D, int STRIDE, int U, bool SPLIT>
__global__ __launch_bounds__(256) void k_agg(const float* __restrict__ tbl,
                                             const int* __restrict__ offs,
                                             const int* __restrict__ ssrc,
                                             const float* __restrict__ inv,
                                             float* __restrict__ outf,
                                             u16* __restrict__ oh, u16* __restrict__ ol) {
    constexpr int G = 256 / D;    // edges per iteration
    constexpr int LPG = 64 / G;   // lanes per edge (= D/4)
    int wid = (blockIdx.x * 256 + threadIdx.x) >> 6;
    if (wid >= N_NODES) return;
    const int coff = blockIdx.y * D;
    int lane = threadIdx.x & 63;
    int eg = lane / LPG;
    int cl = lane % LPG;
    int beg = offs[wid], end = offs[wid + 1];
    float4 acc[U];
#pragma unroll
    for (int j = 0; j < U; ++j) acc[j] = make_float4(0.f, 0.f, 0.f, 0.f);
    for (int e = beg + eg; e < end; e += U * G) {
        int idx[U]; float msk[U];
#pragma unroll
        for (int j = 0; j < U; ++j) {
            int ee = e + j * G;
            bool ok = ee < end;
            idx[j] = ssrc[ok ? ee : e];
            msk[j] = ok ? 1.f : 0.f;
        }
#pragma unroll
        for (int j = 0; j < U; ++j) {
            const float4 t = *(const float4*)(tbl + (size_t)idx[j] * STRIDE + coff + cl * 4);
            acc[j].x = fmaf(t.x, msk[j], acc[j].x);
            acc[j].y = fmaf(t.y, msk[j], acc[j].y);
            acc[j].z = fmaf(t.z, msk[j], acc[j].z);
            acc[j].w = fmaf(t.w, msk[j], acc[j].w);
        }
    }
#pragma unroll
    for (int j = 1; j < U; ++j) {
        acc[0].x += acc[j].x; acc[0].y += acc[j].y;
        acc[0].z += acc[j].z; acc[0].w += acc[j].w;
    }
    float a0 = acc[0].x, a1 = acc[0].y, a2 = acc[0].z, a3 = acc[0].w;
#pragma unroll
    for (int m = LPG; m < 64; m <<= 1) {
        a0 += __shfl_xor(a0, m, 64);
        a1 += __shfl_xor(a1, m, 64);
        a2 += __shfl_xor(a2, m, 64);
        a3 += __shfl_xor(a3, m, 64);
    }
    float wv = inv[wid];
    a0 *= wv; a1 *= wv; a2 *= wv; a3 *= wv;
    if (!SPLIT) {
        if (eg == 0)
            *(float4*)(outf + (size_t)wid * STRIDE + coff + cl * 4) = make_float4(a0, a1, a2, a3);
    } else {
        ushort2 s0 = split_bf(a0), s1 = split_bf(a1), s2 = split_bf(a2), s3 = split_bf(a3);
        if (eg == 0) {
            *(ushort4*)(oh + (size_t)wid * STRIDE + coff + cl * 4) = make_ushort4(s0.x, s1.x, s2.x, s3.x);
        } else if (eg == 1) {
            *(ushort4*)(ol + (size_t)wid * STRIDE + coff + cl * 4) = make_ushort4(s0.y, s1.y, s2.y, s3.y);
        }
    }
}

// ---------------- operand prep ----------------
__global__ void k_xsplit(const float* __restrict__ in, u16* __restrict__ oh,
                         u16* __restrict__ ol, int n4) {
    int i = blockIdx.x * 256 + threadIdx.x;
    if (i >= n4) return;
    float4 v = ((const float4*)in)[i];
    ushort2 s0 = split_bf(v.x), s1 = split_bf(v.y), s2 = split_bf(v.z), s3 = split_bf(v.w);
    ((ushort4*)oh)[i] = make_ushort4(s0.x, s1.x, s2.x, s3.x);
    ((ushort4*)ol)[i] = make_ushort4(s0.y, s1.y, s2.y, s3.y);
}

// transpose + split all 6 weights in one dispatch (blockIdx.y selects weight).
__global__ void k_wsplit(const float* __restrict__ W0, const float* __restrict__ W1,
                         const float* __restrict__ W2, const float* __restrict__ W3,
                         const float* __restrict__ W4, const float* __restrict__ W5,
                         u16* o0h, u16* o0l, u16* o1h, u16* o1l, u16* o2h, u16* o2l,
                         u16* o3h, u16* o3l, u16* o4h, u16* o4l, u16* o5h, u16* o5l) {
    const float* W; u16 *oh, *ol; int K, N;
    switch (blockIdx.y) {
        case 0: W = W0; oh = o0h; ol = o0l; K = 128; N = 512; break;
        case 1: W = W1; oh = o1h; ol = o1l; K = 128; N = 512; break;
        case 2: W = W2; oh = o2h; ol = o2l; K = 512; N = 256; break;
        case 3: W = W3; oh = o3h; ol = o3l; K = 512; N = 256; break;
        case 4: W = W4; oh = o4h; ol = o4l; K = 256; N = 64; break;
        default: W = W5; oh = o5h; ol = o5l; K = 256; N = 64; break;
    }
    int i = blockIdx.x * 256 + threadIdx.x;
    if (i >= K * N) return;
    int k = i / N, n = i - k * N;
    ushort2 s = split_bf(W[i]);
    size_t o = (size_t)n * K + k;   // output is W^T [N][K]
    oh[o] = s.x;
    ol[o] = s.y;
}

// ---------------- split-bf16 MFMA GEMM: 128x128 tile, single-buffer, 4 blocks/CU ------
__global__ __launch_bounds__(256, 4) void k_gemm_s(
    int M, int nct,
    const u16* __restrict__ A1h, const u16* __restrict__ A1l,
    const u16* __restrict__ B1h, const u16* __restrict__ B1l, int K1,
    const u16* __restrict__ A2h, const u16* __restrict__ A2l,
    const u16* __restrict__ B2h, const u16* __restrict__ B2l, int K2,
    const float* __restrict__ bias, int act, int colsplit,
    float* __restrict__ out1f, u16* __restrict__ out1h, u16* __restrict__ out1l, int n1,
    float* __restrict__ out2f, int n2) {
    __shared__ u16 Ash[4096], Asl[4096], Bsh[4096], Bsl[4096];
    const int tid = threadIdx.x;
    const int lane = tid & 63;
    const int w = tid >> 6;
    const int wm = w & 1, wn = w >> 1;
    const int fr = lane & 15;
    const int q = lane >> 4;

    const int mT = (M + 127) >> 7;
    const int lin = blockIdx.x;
    const int grp = lin / (8 * nct);
    const int idx = lin - grp * (8 * nct);
    const int ct = idx >> 3;          // col-tile
    const int s8 = idx & 7;           // XCD slot
    const int rowt = grp * 8 + s8;
    if (rowt >= mT) return;
    const int brow = rowt * 128;
    const int bcol = ct * 128;

    const int T1 = K1 >> 5, T = T1 + (K2 >> 5);

    const int c0 = (w * 2 + 0) * 64 + lane;
    const int c1 = (w * 2 + 1) * 64 + lane;
    const int r0 = c0 >> 2, g0 = (c0 & 3) ^ ((r0 >> 1) & 3);
    const int r1 = c1 >> 2, g1 = (c1 & 3) ^ ((r1 >> 1) & 3);
    int ar0 = brow + r0; if (ar0 >= M) ar0 = M - 1;
    int ar1 = brow + r1; if (ar1 >= M) ar1 = M - 1;
    const int br0 = bcol + r0, br1 = bcol + r1;
    const int ub0 = (w * 2 + 0) * 512;
    const int ub1 = (w * 2 + 1) * 512;

    f32x4 acc[4][4] = {};

    for (int kt = 0; kt < T; ++kt) {
        const u16 *Ah, *Al, *Bh, *Bl; int K, k0;
        if (kt < T1) { Ah = A1h; Al = A1l; Bh = B1h; Bl = B1l; K = K1; k0 = kt * 32; }
        else         { Ah = A2h; Al = A2l; Bh = B2h; Bl = B2l; K = K2; k0 = (kt - T1) * 32; }
        __syncthreads();
        {
            size_t ga0 = (size_t)ar0 * K + k0 + g0 * 8;
            size_t ga1 = (size_t)ar1 * K + k0 + g1 * 8;
            size_t gb0 = (size_t)br0 * K + k0 + g0 * 8;
            size_t gb1 = (size_t)br1 * K + k0 + g1 * 8;
            async_load16(Ah + ga0, &Ash[ub0]);
            async_load16(Ah + ga1, &Ash[ub1]);
            async_load16(Al + ga0, &Asl[ub0]);
            async_load16(Al + ga1, &Asl[ub1]);
            async_load16(Bh + gb0, &Bsh[ub0]);
            async_load16(Bh + gb1, &Bsh[ub1]);
            async_load16(Bl + gb0, &Bsl[ub0]);
            async_load16(Bl + gb1, &Bsl[ub1]);
        }
        __syncthreads();
        bf16x8 fah[4], fal[4], fbh[4], fbl[4];
#pragma unroll
        for (int rt = 0; rt < 4; ++rt) {
            int row = wm * 64 + rt * 16 + fr;
            int ad = row * 32 + ((q ^ ((row >> 1) & 3)) * 8);
            fah[rt] = __builtin_bit_cast(bf16x8, *(const uint4*)&Ash[ad]);
            fal[rt] = __builtin_bit_cast(bf16x8, *(const uint4*)&Asl[ad]);
        }
#pragma unroll
        for (int ctf = 0; ctf < 4; ++ctf) {
            int row = wn * 64 + ctf * 16 + fr;
            int ad = row * 32 + ((q ^ ((row >> 1) & 3)) * 8);
            fbh[ctf] = __builtin_bit_cast(bf16x8, *(const uint4*)&Bsh[ad]);
            fbl[ctf] = __builtin_bit_cast(bf16x8, *(const uint4*)&Bsl[ad]);
        }
#pragma unroll
        for (int rt = 0; rt < 4; ++rt)
#pragma unroll
            for (int ctf = 0; ctf < 4; ++ctf) {
                acc[rt][ctf] = __builtin_amdgcn_mfma_f32_16x16x32_bf16(fah[rt], fbh[ctf], acc[rt][ctf], 0, 0, 0);
                acc[rt][ctf] = __builtin_amdgcn_mfma_f32_16x16x32_bf16(fah[rt], fbl[ctf], acc[rt][ctf], 0, 0, 0);
                acc[rt][ctf] = __builtin_amdgcn_mfma_f32_16x16x32_bf16(fal[rt], fbh[ctf], acc[rt][ctf], 0, 0, 0);
            }
    }

    // epilogue: frag C/D layout col=lane&15, row=q*4+reg  [m89]
#pragma unroll
    for (int rt = 0; rt < 4; ++rt) {
        int rowb = brow + wm * 64 + rt * 16 + q * 4;
#pragma unroll
        for (int ctf = 0; ctf < 4; ++ctf) {
            int col = bcol + wn * 64 + ctf * 16 + fr;
            float b = bias ? bias[col] : 0.f;
#pragma unroll
            for (int r = 0; r < 4; ++r) {
                int row = rowb + r;
                if (row >= M) continue;
                float v = acc[rt][ctf][r] + b;
                if (act) v = leaky(v);
                if (col < colsplit) {
                    if (out1f) out1f[(size_t)row * n1 + col] = v;
                    if (out1h) {
                        ushort2 s = split_bf(v);
                        out1h[(size_t)row * n1 + col] = s.x;
                        out1l[(size_t)row * n1 + col] = s.y;
                    }
                } else {
                    out2f[(size_t)row * n2 + (col - colsplit)] = v;
                }
            }
        }
    }
}

// ---------------- h2 epilogue: h2 = leaky(y2 + a2 + b2) -> split planes ----------------
__global__ __launch_bounds__(256) void k_post2(const float* __restrict__ y2,
                                               const float* __restrict__ a2,
                                               const float* __restrict__ b2,
                                               u16* __restrict__ oh, u16* __restrict__ ol) {
    int i = blockIdx.x * 256 + threadIdx.x;
    if (i >= N_NODES * 64) return;
    float4 y = ((const float4*)y2)[i];
    float4 a = ((const float4*)a2)[i];
    const float4 b = *(const float4*)(b2 + (i & 63) * 4);
    float v0 = leaky(y.x + a.x + b.x);
    float v1 = leaky(y.y + a.y + b.y);
    float v2 = leaky(y.z + a.z + b.z);
    float v3 = leaky(y.w + a.w + b.w);
    ushort2 s0 = split_bf(v0), s1 = split_bf(v1), s2 = split_bf(v2), s3 = split_bf(v3);
    ((ushort4*)oh)[i] = make_ushort4(s0.x, s1.x, s2.x, s3.x);
    ((ushort4*)ol)[i] = make_ushort4(s0.y, s1.y, s2.y, s3.y);
}

// ---------------- fused head: h3 = leaky(y3+a3+b3); -> pre_fc -> leaky(fc1) -> fc2 ------
__global__ __launch_bounds__(256) void k_head(const float* __restrict__ y3,
                                              const float* __restrict__ a3,
                                              const float* __restrict__ b3,
                                              const float* __restrict__ Wp, const float* __restrict__ bp,
                                              const float* __restrict__ Wf1, const float* __restrict__ bf1,
                                              const float* __restrict__ Wf2, const float* __restrict__ bf2,
                                              float* __restrict__ out) {
    __shared__ float sWp[64 * 32], sW1[32 * 32], sW2[32 * 2];
    __shared__ float sbp[32], sb1[32], sb2[2], sb3[64];
    int tid = threadIdx.x;
    for (int i = tid; i < 64 * 32; i += 256) sWp[i] = Wp[i];
    for (int i = tid; i < 32 * 32; i += 256) sW1[i] = Wf1[i];
    for (int i = tid; i < 64; i += 256) { sW2[i] = Wf2[i]; sb3[i] = b3[i]; }
    if (tid < 32) { sbp[tid] = bp[tid]; sb1[tid] = bf1[tid]; }
    if (tid < 2) sb2[tid] = bf2[tid];
    __syncthreads();
    int row = blockIdx.x * 256 + tid;
    if (row >= N_NODES) return;
    const float4* y4 = (const float4*)(y3 + (size_t)row * 64);
    const float4* a4 = (const float4*)(a3 + (size_t)row * 64);
    float xr[64];
#pragma unroll
    for (int i = 0; i < 16; ++i) {
        float4 yv = y4[i], av = a4[i];
        xr[i * 4 + 0] = leaky(yv.x + av.x + sb3[i * 4 + 0]);
        xr[i * 4 + 1] = leaky(yv.y + av.y + sb3[i * 4 + 1]);
        xr[i * 4 + 2] = leaky(yv.z + av.z + sb3[i * 4 + 2]);
        xr[i * 4 + 3] = leaky(yv.w + av.w + sb3[i * 4 + 3]);
    }
    float h4[32];
    for (int o = 0; o < 32; ++o) {
        float s = sbp[o];
#pragma unroll
        for (int i = 0; i < 64; ++i) s += xr[i] * sWp[i * 32 + o];
        h4[o] = s;
    }
    float h5[32];
    for (int o = 0; o < 32; ++o) {
        float s = sb1[o];
#pragma unroll
        for (int i = 0; i < 32; ++i) s += h4[i] * sW1[i * 32 + o];
        h5[o] = leaky(s);
    }
#pragma unroll
    for (int o = 0; o < 2; ++o) {
        float s = sb2[o];
#pragma unroll
        for (int i = 0; i < 32; ++i) s += h5[i] * sW2[i * 2 + o];
        out[(size_t)row * 2 + o] = s;
    }
}

// ---------------- launch ----------------
extern "C" void kernel_launch(void* const* d_in, const int* in_sizes, int n_in,
                              void* d_out, int out_size, void* d_ws, size_t ws_size,
                              hipStream_t stream) {
    const float* x   = (const float*)d_in[0];
    const int*   ei  = (const int*)d_in[1];
    const float* W1l = (const float*)d_in[5];
    const float* b1  = (const float*)d_in[6];
    const float* W1r = (const float*)d_in[7];
    const float* W2l = (const float*)d_in[8];
    const float* b2  = (const float*)d_in[9];
    const float* W2r = (const float*)d_in[10];
    const float* W3l = (const float*)d_in[11];
    const float* b3  = (const float*)d_in[12];
    const float* W3r = (const float*)d_in[13];
    const float* Wp  = (const float*)d_in[14];
    const float* bp  = (const float*)d_in[15];
    const float* Wf1 = (const float*)d_in[16];
    const float* bf1 = (const float*)d_in[17];
    const float* Wf2 = (const float*)d_in[18];
    const float* bf2 = (const float*)d_in[19];
    float* out = (float*)d_out;
    (void)in_sizes; (void)n_in; (void)out_size; (void)ws_size;

    const int* src = ei;
    const int* dst = ei + N_EDGES;

    char* base = (char*)d_ws;
    size_t off = 0;
    auto alloc = [&](size_t bytes) -> void* {
        void* r = base + off;
        off = (off + bytes + 255) & ~(size_t)255;
        return r;
    };
    const size_t NN = N_NODES;
    int*   cnt    = (int*)alloc(NN * 4);
    int*   offs   = (int*)alloc((NN + 1) * 4);
    int*   cursor = (int*)alloc(NN * 4);
    float* inv    = (float*)alloc(NN * 4);
    int*   bsum   = (int*)alloc(64 * 4);
    int*   ssrc   = (int*)alloc((size_t)N_EDGES * 4);
    u16* w1lh = (u16*)alloc(128 * 512 * 2); u16* w1ll = (u16*)alloc(128 * 512 * 2);
    u16* w1rh = (u16*)alloc(128 * 512 * 2); u16* w1rl = (u16*)alloc(128 * 512 * 2);
    u16* w2ch = (u16*)alloc(512 * 512 * 2); u16* w2cl = (u16*)alloc(512 * 512 * 2);
    u16* w3ch = (u16*)alloc(128 * 256 * 2); u16* w3cl = (u16*)alloc(128 * 256 * 2);

    // Live-range-aliased regions (~205 MB)
    char* regA = (char*)alloc(NN * 256 * 4);       // xh|xl|axh|axl -> z2 -> h2h|h2l
    char* regB = (char*)alloc(NN * 512 * 2 * 2);   // h1h|h1l -> a2
    char* regD = (char*)alloc(NN * 256 * 4);       // y2 -> z3|y3|a3

    u16* xh  = (u16*)regA;
    u16* xl  = xh + NN * 128;
    u16* axh = xl + NN * 128;
    u16* axl = axh + NN * 128;
    u16* h1h = (u16*)regB;
    u16* h1l = h1h + NN * 512;
    float* z2 = (float*)regA;
    float* a2 = (float*)regB;
    u16* h2h = (u16*)regA;
    u16* h2l = h2h + NN * 256;
    float* y2f = (float*)regD;
    float* z3f = (float*)regD;
    float* y3f = z3f + NN * 64;
    float* a3f = y3f + NN * 64;

    // CSR build
    hipMemsetAsync(cnt, 0, NN * 4, stream);
    k_count<<<(N_EDGES + 255) / 256, 256, 0, stream>>>(dst, cnt);
    const int nb = (N_NODES + 1023) / 1024;   // 49
    k_scan1<<<nb, 1024, 0, stream>>>(cnt, offs, bsum);
    k_scan2<<<1, 64, 0, stream>>>(bsum, nb);
    k_scan3<<<(N_NODES + 255) / 256, 256, 0, stream>>>(cnt, offs, cursor, inv, bsum);
    k_fill<<<(N_EDGES + 255) / 256, 256, 0, stream>>>(src, dst, cursor, ssrc);

    // operand prep
    k_xsplit<<<(N_NODES * 128 / 4 + 255) / 256, 256, 0, stream>>>(x, xh, xl, N_NODES * 128 / 4);
    k_wsplit<<<dim3(512, 6), 256, 0, stream>>>(W1l, W1r, W2l, W2r, W3l, W3r,
        w1lh, w1ll, w1rh, w1rl,
        w2ch, w2cl, w2ch + 256 * 512, w2cl + 256 * 512,
        w3ch, w3cl, w3ch + 64 * 256, w3cl + 64 * 256);

    const int aggGrid = (N_NODES + 3) / 4;
    const int mT = (N_NODES + 127) / 128;              // 391
    const int grid4 = ((mT + 7) / 8) * 32;             // nct=4 -> 1600
    const int grid1 = ((mT + 7) / 8) * 8;              // nct=1 -> 400

    // layer 1: aggX = S x (split, 2 column chunks); h1 = leaky(aggX@W1l + x@W1r + b1)
    k_agg<64, 128, 8, true><<<dim3(aggGrid, 2), 256, 0, stream>>>(
        x, offs, ssrc, inv, nullptr, axh, axl);
    k_gemm_s<<<grid4, 256, 0, stream>>>(N_NODES, 4,
        axh, axl, w1lh, w1ll, 128, xh, xl, w1rh, w1rl, 128,
        b1, 1, 512, nullptr, h1h, h1l, 512, nullptr, 0);

    // layer 2 (fused): [z2 | y2] = h1 @ [W2l | W2r]; a2 = S z2; h2 = leaky(y2+a2+b2)
    k_gemm_s<<<grid4, 256, 0, stream>>>(N_NODES, 4,
        h1h, h1l, w2ch, w2cl, 512, nullptr, nullptr, nullptr, nullptr, 0,
        nullptr, 0, 256, z2, nullptr, nullptr, 256, y2f, 256);
    k_agg<128, 256, 8, false><<<dim3(aggGrid, 2), 256, 0, stream>>>(
        z2, offs, ssrc, inv, a2, nullptr, nullptr);
    k_post2<<<(N_NODES * 64 + 255) / 256, 256, 0, stream>>>(y2f, a2, b2, h2h, h2l);

    // layer 3 (fused): [z3 | y3] = h2 @ [W3l | W3r]; a3 = S z3; h3 folded into head
    k_gemm_s<<<grid1, 256, 0, stream>>>(N_NODES, 1,
        h2h, h2l, w3ch, w3cl, 256, nullptr, nullptr, nullptr, nullptr, 0,
        nullptr, 0, 64, z3f, nullptr, nullptr, 64, y3f, 64);
    k_agg<32, 64, 8, false><<<dim3(aggGrid, 2), 256, 0, stream>>>(
        z3f, offs, ssrc, inv, a3f, nullptr, nullptr);

    // head: h3 = leaky(y3+a3+b3) -> pre_fc -> leaky(fc1) -> fc2
    k_head<<<(N_NODES + 255) / 256, 256, 0, stream>>>(y3f, a3f, b3,
        Wp, bp, Wf1, bf1, Wf2, bf2, out);
}